// Round 1
// baseline (814.496 us; speedup 1.0000x reference)
//
#include <hip/hip_runtime.h>

#define NB 8
#define NC 128
#define NN 256
#define NK 96
#define NA 512
#define NM 768   // NN + NA

__device__ __forceinline__ float wave_reduce_add(float s) {
    for (int o = 32; o > 0; o >>= 1) s += __shfl_down(s, o, 64);
    return s;
}

// ---- normalize memory features, store transposed (C, A) for coalesced sim ----
__global__ void k_norm_mem(const float* __restrict__ tf, float* __restrict__ memN_T) {
    int a = blockIdx.x, c = threadIdx.x;
    float v = tf[a * NC + c];
    float s = wave_reduce_add(v * v);
    __shared__ float p[2];
    if ((threadIdx.x & 63) == 0) p[threadIdx.x >> 6] = s;
    __syncthreads();
    float norm = sqrtf(p[0] + p[1]);
    memN_T[c * NA + a] = v / fmaxf(norm, 1e-12f);
}

// ---- normalize test features per (b,n) over C, store (B*N, C) ----
__global__ void k_norm_x(const float* __restrict__ feat, float* __restrict__ Xn) {
    int g = blockIdx.x, c = threadIdx.x;   // g = b*NN + n
    int b = g >> 8, n = g & 255;
    float v = feat[(b * NC + c) * NN + n];
    float s = wave_reduce_add(v * v);
    __shared__ float p[2];
    if ((threadIdx.x & 63) == 0) p[threadIdx.x >> 6] = s;
    __syncthreads();
    float norm = sqrtf(p[0] + p[1]);
    Xn[g * NC + c] = v / fmaxf(norm, 1e-12f);
}

// ---- memory hyperedge degrees -> 1/(deg+eps) ----
__global__ void k_dmem(const float* __restrict__ mem_adj, float* __restrict__ dmem_inv) {
    int j = threadIdx.x;
    if (j >= NK) return;
    float s = 0.f;
    for (int a = 0; a < NA; a++) s += mem_adj[a * NK + j];
    dmem_inv[j] = 1.0f / (s + 1e-8f);
}

// ---- adj column degrees + node degrees ----
__global__ void k_adj_deg(const float* __restrict__ adj, float* __restrict__ sc_adj,
                          float* __restrict__ inv_edge, float* __restrict__ isn) {
    int b = blockIdx.x, t = threadIdx.x;
    if (t < NK) {
        float s = 0.f;
        for (int n = 0; n < NN; n++) s += adj[(b * NN + n) * NK + t];
        sc_adj[b * NK + t] = 1.0f / (s + 1e-8f);        // d_e_inv for H columns
        inv_edge[b * NK + t] = 1.0f / fmaxf(s, 1e-8f);  // X_E edge scale (clip)
    }
    // node degree (t = n, 0..255)
    float s2 = 0.f;
    const float* row = adj + (size_t)(b * NN + t) * NK;
    for (int j = 0; j < NK; j++) s2 += row[j];
    isn[b * NN + t] = 1.0f / sqrtf(fmaxf(s2, 1e-8f));
}

// ---- cosine similarity sim[b*N+n][a] = <Xn_row, memN_col> ----
__global__ __launch_bounds__(512) void k_sim(const float* __restrict__ Xn,
                                             const float* __restrict__ memN_T,
                                             float* __restrict__ sim) {
    __shared__ float xr[8][NC];
    int g0 = blockIdx.x * 8;
    int t = threadIdx.x;
    for (int i = t; i < 8 * NC; i += 512) xr[i / NC][i % NC] = Xn[g0 * NC + i];
    __syncthreads();
    float acc[8] = {0, 0, 0, 0, 0, 0, 0, 0};
    int a = t;  // 0..511
    for (int c = 0; c < NC; c++) {
        float m = memN_T[c * NA + a];
#pragma unroll
        for (int r = 0; r < 8; r++) acc[r] += xr[r][c] * m;
    }
#pragma unroll
    for (int r = 0; r < 8; r++) sim[(size_t)(g0 + r) * NA + a] = acc[r];
}

// ---- stable top-4 (ties -> lower index), registers only ----
__device__ __forceinline__ void top4_update(float v, int a, float& t0, float& t1, float& t2,
                                            float& t3, int& i0, int& i1, int& i2, int& i3) {
    if (v > t3) {
        if (v > t0)      { t3=t2;i3=i2; t2=t1;i2=i1; t1=t0;i1=i0; t0=v;i0=a; }
        else if (v > t1) { t3=t2;i3=i2; t2=t1;i2=i1; t1=v;i1=a; }
        else if (v > t2) { t3=t2;i3=i2; t2=v;i2=a; }
        else             { t3=v;i3=a; }
    }
}

__global__ void k_knn(const float* __restrict__ sim, int* __restrict__ knn) {
    int g = blockIdx.x * blockDim.x + threadIdx.x;  // b*NN + n
    if (g >= NB * NN) return;
    const float* row = sim + (size_t)g * NA;
    float t0=-1e30f,t1=-1e30f,t2=-1e30f,t3=-1e30f; int i0=0,i1=0,i2=0,i3=0;
    for (int a = 0; a < NA; a++) top4_update(row[a], a, t0,t1,t2,t3, i0,i1,i2,i3);
    knn[g*4+0]=i0; knn[g*4+1]=i1; knn[g*4+2]=i2; knn[g*4+3]=i3;
}

__global__ void k_rev(const float* __restrict__ sim, int* __restrict__ rev) {
    int g = blockIdx.x * blockDim.x + threadIdx.x;  // b*NA + a
    if (g >= NB * NA) return;
    int b = g / NA, a = g % NA;
    const float* base = sim + (size_t)b * NN * NA + a;
    float t0=-1e30f,t1=-1e30f,t2=-1e30f,t3=-1e30f; int i0=0,i1=0,i2=0,i3=0;
    for (int n = 0; n < NN; n++) top4_update(base[(size_t)n * NA], n, t0,t1,t2,t3, i0,i1,i2,i3);
    rev[g*4+0]=i0; rev[g*4+1]=i1; rev[g*4+2]=i2; rev[g*4+3]=i3;
}

// ---- bottom-right A x A block of W (batch-independent), written to all batches ----
__global__ __launch_bounds__(256) void k_memW(const float* __restrict__ mem_adj,
                                              const float* __restrict__ dmem_inv,
                                              float* __restrict__ W) {
    __shared__ float ta[16][NK + 1];
    __shared__ float tb[16][NK + 1];
    int a0 = blockIdx.y * 16, a1 = blockIdx.x * 16;
    int tid = threadIdx.y * 16 + threadIdx.x;
    for (int i = tid; i < 16 * NK; i += 256) {
        int r = i / NK, j = i % NK;
        ta[r][j] = mem_adj[(a0 + r) * NK + j] * dmem_inv[j];
        tb[r][j] = mem_adj[(a1 + r) * NK + j];
    }
    __syncthreads();
    float s = 0.f;
    for (int j = 0; j < NK; j++) s += ta[threadIdx.y][j] * tb[threadIdx.x][j];
    int row = NN + a0 + threadIdx.y, col = NN + a1 + threadIdx.x;
    for (int b = 0; b < NB; b++) W[(size_t)b * NM * NM + (size_t)row * NM + col] = s;
}

// ---- top-left N x N block of W per batch ----
__global__ __launch_bounds__(256) void k_adjW(const float* __restrict__ adj,
                                              const float* __restrict__ sc_adj,
                                              float* __restrict__ W) {
    __shared__ float ta[16][NK + 1];
    __shared__ float tb[16][NK + 1];
    int b = blockIdx.z;
    int n0 = blockIdx.y * 16, n1 = blockIdx.x * 16;
    int tid = threadIdx.y * 16 + threadIdx.x;
    const float* adjb = adj + (size_t)b * NN * NK;
    const float* scb = sc_adj + b * NK;
    for (int i = tid; i < 16 * NK; i += 256) {
        int r = i / NK, j = i % NK;
        ta[r][j] = adjb[(n0 + r) * NK + j] * scb[j];
        tb[r][j] = adjb[(n1 + r) * NK + j];
    }
    __syncthreads();
    float s = 0.f;
    for (int j = 0; j < NK; j++) s += ta[threadIdx.y][j] * tb[threadIdx.x][j];
    W[(size_t)b * NM * NM + (size_t)(n0 + threadIdx.y) * NM + (n1 + threadIdx.x)] = s;
}

// ---- cross columns: each has exactly 5 ones (deg 5), 25-entry outer-product scatter ----
__global__ void k_scatter(const int* __restrict__ knn, const int* __restrict__ rev,
                          float* __restrict__ W) {
    int g = blockIdx.x * blockDim.x + threadIdx.x;  // b*NM + col
    if (g >= NB * NM) return;
    int b = g / NM, col = g % NM;
    const float cval = 1.0f / (5.0f + 1e-8f);
    int r[5];
    r[0] = col;
    if (col < NN) {
        const int* kk = knn + (size_t)(b * NN + col) * 4;
#pragma unroll
        for (int t = 0; t < 4; t++) r[t + 1] = NN + kk[t];
    } else {
        const int* rr = rev + (size_t)(b * NA + (col - NN)) * 4;
#pragma unroll
        for (int t = 0; t < 4; t++) r[t + 1] = rr[t];
    }
    float* Wb = W + (size_t)b * NM * NM;
#pragma unroll
    for (int i = 0; i < 5; i++)
#pragma unroll
        for (int j = 0; j < 5; j++) atomicAdd(&Wb[(size_t)r[i] * NM + r[j]], cval);
}

// ---- d_is[row] = 1/sqrt(rowsum(W) + 1 (identity) + eps); one wave per row ----
__global__ __launch_bounds__(256) void k_dis(const float* __restrict__ W, float* __restrict__ dis) {
    int wid = (blockIdx.x * 256 + threadIdx.x) >> 6;  // global row = b*NM + i
    int lane = threadIdx.x & 63;
    if (wid >= NB * NM) return;
    const float* row = W + (size_t)wid * NM;
    float s = 0.f;
    for (int t = lane; t < NM; t += 64) s += row[t];
    s = wave_reduce_add(s);
    if (lane == 0) dis[wid] = 1.0f / sqrtf(s + 1.0f + 1e-8f);
}

// ---- Y0 = joint_X^T  (M x C per batch), XhatT = 0.9 * Y0 ----
__global__ void k_y0(const float* __restrict__ feat, const float* __restrict__ tf,
                     float* __restrict__ Y0, float* __restrict__ XhatT) {
    int g = blockIdx.x, c = threadIdx.x;  // g = b*NM + m
    int b = g / NM, m = g % NM;
    float v = (m < NN) ? feat[((size_t)b * NC + c) * NN + m] : tf[(size_t)(m - NN) * NC + c];
    Y0[(size_t)g * NC + c] = v;
    XhatT[(size_t)g * NC + c] = 0.9f * v;
}

// ---- propagation: Yout = Amat @ Yin ; XhatT += coef * Yout
//      out[i,c] = dis[i]*( acc[i,c] + dis[i]*Yin[i,c] ),  acc = W @ (dis.*Yin)
__global__ __launch_bounds__(256) void k_prop(const float* __restrict__ W,
                                              const float* __restrict__ dis,
                                              const float* __restrict__ Yin,
                                              float* __restrict__ Yout,
                                              float* __restrict__ XhatT, float coef) {
    __shared__ float WtT[16][36];   // transposed W tile, stride 36 floats = 144B (16B-aligned)
    __shared__ float Zt[16][NC];
    int b = blockIdx.y;
    int i0 = blockIdx.x * 32;
    int tid = threadIdx.x;
    int tm = tid >> 5, tn = tid & 31;
    const float* Wb = W + ((size_t)b * NM + i0) * NM;
    const float* disb = dis + b * NM;
    const float* Yb = Yin + (size_t)b * NM * NC;
    float acc[4][4] = {{0.f}};
    for (int k0 = 0; k0 < NM; k0 += 16) {
#pragma unroll
        for (int it = 0; it < 2; it++) {
            int idx = tid + it * 256;
            int kr = idx >> 5, cc = (idx & 31) << 2;
            float4 yv = *(const float4*)&Yb[(size_t)(k0 + kr) * NC + cc];
            float dk = disb[k0 + kr];
            float4 zv; zv.x = yv.x * dk; zv.y = yv.y * dk; zv.z = yv.z * dk; zv.w = yv.w * dk;
            *(float4*)&Zt[kr][cc] = zv;
        }
        if (tid < 128) {
            int r = tid >> 2, c4 = (tid & 3) << 2;
            float4 wv = *(const float4*)&Wb[(size_t)r * NM + k0 + c4];
            WtT[c4 + 0][r] = wv.x; WtT[c4 + 1][r] = wv.y;
            WtT[c4 + 2][r] = wv.z; WtT[c4 + 3][r] = wv.w;
        }
        __syncthreads();
#pragma unroll
        for (int kk = 0; kk < 16; kk++) {
            float4 wv = *(const float4*)&WtT[kk][tm << 2];
            float4 zv = *(const float4*)&Zt[kk][tn << 2];
            acc[0][0] += wv.x * zv.x; acc[0][1] += wv.x * zv.y; acc[0][2] += wv.x * zv.z; acc[0][3] += wv.x * zv.w;
            acc[1][0] += wv.y * zv.x; acc[1][1] += wv.y * zv.y; acc[1][2] += wv.y * zv.z; acc[1][3] += wv.y * zv.w;
            acc[2][0] += wv.z * zv.x; acc[2][1] += wv.z * zv.y; acc[2][2] += wv.z * zv.z; acc[2][3] += wv.z * zv.w;
            acc[3][0] += wv.w * zv.x; acc[3][1] += wv.w * zv.y; acc[3][2] += wv.w * zv.z; acc[3][3] += wv.w * zv.w;
        }
        __syncthreads();
    }
    int ibase = i0 + (tm << 2);
    float* Youtb = Yout + (size_t)b * NM * NC;
    float* Xb = XhatT + (size_t)b * NM * NC;
#pragma unroll
    for (int r = 0; r < 4; r++) {
        int i = ibase + r;
        float di = disb[i];
        size_t off = (size_t)i * NC + (tn << 2);
        float4 yv = *(const float4*)&Yb[off];
        float4 o;
        o.x = di * (acc[r][0] + di * yv.x);
        o.y = di * (acc[r][1] + di * yv.y);
        o.z = di * (acc[r][2] + di * yv.z);
        o.w = di * (acc[r][3] + di * yv.w);
        *(float4*)&Youtb[off] = o;
        float4 xh = *(const float4*)&Xb[off];
        xh.x += coef * o.x; xh.y += coef * o.y; xh.z += coef * o.z; xh.w += coef * o.w;
        *(float4*)&Xb[off] = xh;
    }
}

// ---- write X_hat (B,C,N) from XhatT (B,M,C), n < N only ----
__global__ void k_xhat_out(const float* __restrict__ XhatT, float* __restrict__ out) {
    int bc = blockIdx.x;  // b*NC + c
    int b = bc / NC, c = bc % NC;
    int n = threadIdx.x;
    out[(size_t)bc * NN + n] = XhatT[((size_t)b * NM + n) * NC + c];
}

// ---- X_E[b,k,c] = inv_edge[b,k] * sum_n adj[b,n,k]*isn[b,n]*XhatT[b,n,c] ----
__global__ void k_xe(const float* __restrict__ adj, const float* __restrict__ isn,
                     const float* __restrict__ inv_edge, const float* __restrict__ XhatT,
                     float* __restrict__ outE) {
    int bk = blockIdx.x;  // b*NK + k
    int b = bk / NK, k = bk % NK;
    int c = threadIdx.x;
    float s = 0.f;
    for (int n = 0; n < NN; n++) {
        float av = adj[(size_t)(b * NN + n) * NK + k];
        if (av != 0.0f) s += av * isn[b * NN + n] * XhatT[((size_t)b * NM + n) * NC + c];
    }
    outE[(size_t)bk * NC + c] = inv_edge[bk] * s;
}

extern "C" void kernel_launch(void* const* d_in, const int* in_sizes, int n_in,
                              void* d_out, int out_size, void* d_ws, size_t ws_size,
                              hipStream_t stream) {
    (void)in_sizes; (void)n_in; (void)out_size; (void)ws_size;
    const float* features = (const float*)d_in[0];  // (B,C,N)
    const float* adj      = (const float*)d_in[1];  // (B,N,K)
    const float* tf       = (const float*)d_in[2];  // (A,C)
    const float* mem_adj  = (const float*)d_in[3];  // (A,K)
    float* out_xhat = (float*)d_out;                 // (B,C,N)
    float* out_xe   = out_xhat + (size_t)NB * NC * NN;  // (B,K,C)

    float* p = (float*)d_ws;
    float* memN_T  = p; p += (size_t)NC * NA;
    float* Xn      = p; p += (size_t)NB * NN * NC;
    float* sim     = p; p += (size_t)NB * NN * NA;
    float* sc_adj  = p; p += NB * NK;
    float* inv_edge= p; p += NB * NK;
    float* dmem_inv= p; p += NK;
    float* isn     = p; p += NB * NN;
    float* dis     = p; p += NB * NM;
    float* W       = p; p += (size_t)NB * NM * NM;
    float* Y0      = p; p += (size_t)NB * NM * NC;
    float* Y1      = p; p += (size_t)NB * NM * NC;
    float* XhatT   = p; p += (size_t)NB * NM * NC;
    int* knn = (int*)p;
    int* rev = knn + NB * NN * 4;

    hipMemsetAsync(W, 0, sizeof(float) * (size_t)NB * NM * NM, stream);
    k_norm_mem<<<NA, NC, 0, stream>>>(tf, memN_T);
    k_norm_x<<<NB * NN, NC, 0, stream>>>(features, Xn);
    k_dmem<<<1, 128, 0, stream>>>(mem_adj, dmem_inv);
    k_adj_deg<<<NB, 256, 0, stream>>>(adj, sc_adj, inv_edge, isn);
    k_sim<<<NB * NN / 8, 512, 0, stream>>>(Xn, memN_T, sim);
    k_knn<<<NB * NN / 256, 256, 0, stream>>>(sim, knn);
    k_rev<<<NB * NA / 256, 256, 0, stream>>>(sim, rev);
    k_memW<<<dim3(NA / 16, NA / 16), dim3(16, 16), 0, stream>>>(mem_adj, dmem_inv, W);
    k_adjW<<<dim3(NN / 16, NN / 16, NB), dim3(16, 16), 0, stream>>>(adj, sc_adj, W);
    k_scatter<<<NB * NM / 256, 256, 0, stream>>>(knn, rev, W);
    k_dis<<<NB * NM / 4, 256, 0, stream>>>(W, dis);
    k_y0<<<NB * NM, NC, 0, stream>>>(features, tf, Y0, XhatT);
    dim3 pg(NM / 32, NB);
    k_prop<<<pg, 256, 0, stream>>>(W, dis, Y0, Y1, XhatT, 0.09f);
    k_prop<<<pg, 256, 0, stream>>>(W, dis, Y1, Y0, XhatT, 0.009f);
    k_prop<<<pg, 256, 0, stream>>>(W, dis, Y0, Y1, XhatT, 0.001f);
    k_xhat_out<<<NB * NC, NN, 0, stream>>>(XhatT, out_xhat);
    k_xe<<<NB * NK, NC, 0, stream>>>(adj, isn, inv_edge, XhatT, out_xe);
}

// Round 2
// 345.476 us; speedup vs baseline: 2.3576x; 2.3576x over previous
//
#include <hip/hip_runtime.h>

#define NB 8
#define NC 128
#define NN 256
#define NK 96
#define NA 512
#define NM 768   // NN + NA

__device__ __forceinline__ float wave_reduce_add(float s) {
    for (int o = 32; o > 0; o >>= 1) s += __shfl_down(s, o, 64);
    return s;
}

// ---- normalize memory features, store transposed (C, A) for coalesced sim ----
__global__ void k_norm_mem(const float* __restrict__ tf, float* __restrict__ memN_T) {
    int a = blockIdx.x, c = threadIdx.x;
    float v = tf[a * NC + c];
    float s = wave_reduce_add(v * v);
    __shared__ float p[2];
    if ((threadIdx.x & 63) == 0) p[threadIdx.x >> 6] = s;
    __syncthreads();
    float norm = sqrtf(p[0] + p[1]);
    memN_T[c * NA + a] = v / fmaxf(norm, 1e-12f);
}

// ---- normalize test features per (b,n) over C, store (B*N, C) ----
__global__ void k_norm_x(const float* __restrict__ feat, float* __restrict__ Xn) {
    int g = blockIdx.x, c = threadIdx.x;   // g = b*NN + n
    int b = g >> 8, n = g & 255;
    float v = feat[(b * NC + c) * NN + n];
    float s = wave_reduce_add(v * v);
    __shared__ float p[2];
    if ((threadIdx.x & 63) == 0) p[threadIdx.x >> 6] = s;
    __syncthreads();
    float norm = sqrtf(p[0] + p[1]);
    Xn[g * NC + c] = v / fmaxf(norm, 1e-12f);
}

// ---- memory hyperedge degrees -> 1/(deg+eps) ----
__global__ void k_dmem(const float* __restrict__ mem_adj, float* __restrict__ dmem_inv) {
    int j = threadIdx.x;
    if (j >= NK) return;
    float s = 0.f;
    for (int a = 0; a < NA; a++) s += mem_adj[a * NK + j];
    dmem_inv[j] = 1.0f / (s + 1e-8f);
}

// ---- adj column degrees + node degrees ----
__global__ void k_adj_deg(const float* __restrict__ adj, float* __restrict__ sc_adj,
                          float* __restrict__ inv_edge, float* __restrict__ isn) {
    int b = blockIdx.x, t = threadIdx.x;
    if (t < NK) {
        float s = 0.f;
        for (int n = 0; n < NN; n++) s += adj[(b * NN + n) * NK + t];
        sc_adj[b * NK + t] = 1.0f / (s + 1e-8f);        // d_e_inv for H columns
        inv_edge[b * NK + t] = 1.0f / fmaxf(s, 1e-8f);  // X_E edge scale (clip)
    }
    // node degree (t = n, 0..255)
    float s2 = 0.f;
    const float* row = adj + (size_t)(b * NN + t) * NK;
    for (int j = 0; j < NK; j++) s2 += row[j];
    isn[b * NN + t] = 1.0f / sqrtf(fmaxf(s2, 1e-8f));
}

// ---- cosine similarity sim[b*N+n][a] = <Xn_row, memN_col> ----
__global__ __launch_bounds__(512) void k_sim(const float* __restrict__ Xn,
                                             const float* __restrict__ memN_T,
                                             float* __restrict__ sim) {
    __shared__ float xr[8][NC];
    int g0 = blockIdx.x * 8;
    int t = threadIdx.x;
    for (int i = t; i < 8 * NC; i += 512) xr[i / NC][i % NC] = Xn[g0 * NC + i];
    __syncthreads();
    float acc[8] = {0, 0, 0, 0, 0, 0, 0, 0};
    int a = t;  // 0..511
    for (int c = 0; c < NC; c++) {
        float m = memN_T[c * NA + a];
#pragma unroll
        for (int r = 0; r < 8; r++) acc[r] += xr[r][c] * m;
    }
#pragma unroll
    for (int r = 0; r < 8; r++) sim[(size_t)(g0 + r) * NA + a] = acc[r];
}

// ---- sortable key: higher value wins, tie -> lower index (== lax.top_k order) ----
__device__ __forceinline__ unsigned long long pack_key(float v, unsigned idx) {
    unsigned u = __float_as_uint(v);
    u = (u & 0x80000000u) ? ~u : (u | 0x80000000u);
    return ((unsigned long long)u << 32) | (unsigned long long)(0xFFFFFFFFu - idx);
}

__device__ __forceinline__ void ins4(unsigned long long v, unsigned long long* k) {
    if (v > k[3]) {
        if (v > k[1]) {
            if (v > k[0]) { k[3] = k[2]; k[2] = k[1]; k[1] = k[0]; k[0] = v; }
            else         { k[3] = k[2]; k[2] = k[1]; k[1] = v; }
        } else {
            if (v > k[2]) { k[3] = k[2]; k[2] = v; }
            else          { k[3] = v; }
        }
    }
}

// butterfly merge of per-lane sorted-desc top-4 lists -> global top-4 in every lane
__device__ __forceinline__ void merge_top4(unsigned long long* k) {
#pragma unroll
    for (int d = 1; d < 64; d <<= 1) {
        unsigned long long p0 = __shfl_xor(k[0], d, 64);
        unsigned long long p1 = __shfl_xor(k[1], d, 64);
        unsigned long long p2 = __shfl_xor(k[2], d, 64);
        unsigned long long p3 = __shfl_xor(k[3], d, 64);
        // m = {k0,k1,k2,k3,p3,p2,p1,p0} is bitonic; keep max-half
        unsigned long long c0 = k[0] > p3 ? k[0] : p3;
        unsigned long long c1 = k[1] > p2 ? k[1] : p2;
        unsigned long long c2 = k[2] > p1 ? k[2] : p1;
        unsigned long long c3 = k[3] > p0 ? k[3] : p0;
        // sort bitonic-4 descending
        unsigned long long d0 = c0 > c2 ? c0 : c2, d2 = c0 > c2 ? c2 : c0;
        unsigned long long d1 = c1 > c3 ? c1 : c3, d3 = c1 > c3 ? c3 : c1;
        k[0] = d0 > d1 ? d0 : d1; k[1] = d0 > d1 ? d1 : d0;
        k[2] = d2 > d3 ? d2 : d3; k[3] = d2 > d3 ? d3 : d2;
    }
}

// ---- top-4 memory neighbors per test node: one wave per (b,n) row ----
__global__ __launch_bounds__(256) void k_knn(const float* __restrict__ sim, int* __restrict__ knn) {
    int wid = (blockIdx.x * 256 + threadIdx.x) >> 6;  // b*NN + n
    int lane = threadIdx.x & 63;
    if (wid >= NB * NN) return;
    const float* row = sim + (size_t)wid * NA;
    unsigned long long k[4] = {0, 0, 0, 0};
#pragma unroll
    for (int t = 0; t < NA / 64; t++) {
        int a = lane + 64 * t;
        ins4(pack_key(row[a], (unsigned)a), k);
    }
    merge_top4(k);
    if (lane < 4) knn[wid * 4 + lane] = (int)(0xFFFFFFFFu - (unsigned)k[lane]);
}

// ---- top-4 test neighbors per memory node: one wave per (b,a) column ----
__global__ __launch_bounds__(256) void k_rev(const float* __restrict__ sim, int* __restrict__ rev) {
    int wid = (blockIdx.x * 256 + threadIdx.x) >> 6;  // b*NA + a
    int lane = threadIdx.x & 63;
    if (wid >= NB * NA) return;
    int b = wid >> 9, a = wid & 511;
    const float* base = sim + (size_t)b * NN * NA + a;
    unsigned long long k[4] = {0, 0, 0, 0};
#pragma unroll
    for (int t = 0; t < NN / 64; t++) {
        int n = lane + 64 * t;
        ins4(pack_key(base[(size_t)n * NA], (unsigned)n), k);
    }
    merge_top4(k);
    if (lane < 4) rev[wid * 4 + lane] = (int)(0xFFFFFFFFu - (unsigned)k[lane]);
}

// ---- bottom-right A x A block of W (batch-independent), written to all batches ----
__global__ __launch_bounds__(256) void k_memW(const float* __restrict__ mem_adj,
                                              const float* __restrict__ dmem_inv,
                                              float* __restrict__ W) {
    __shared__ float ta[16][NK + 1];
    __shared__ float tb[16][NK + 1];
    int a0 = blockIdx.y * 16, a1 = blockIdx.x * 16;
    int tid = threadIdx.y * 16 + threadIdx.x;
    for (int i = tid; i < 16 * NK; i += 256) {
        int r = i / NK, j = i % NK;
        ta[r][j] = mem_adj[(a0 + r) * NK + j] * dmem_inv[j];
        tb[r][j] = mem_adj[(a1 + r) * NK + j];
    }
    __syncthreads();
    float s = 0.f;
    for (int j = 0; j < NK; j++) s += ta[threadIdx.y][j] * tb[threadIdx.x][j];
    int row = NN + a0 + threadIdx.y, col = NN + a1 + threadIdx.x;
    for (int b = 0; b < NB; b++) W[(size_t)b * NM * NM + (size_t)row * NM + col] = s;
}

// ---- top-left N x N block of W per batch ----
__global__ __launch_bounds__(256) void k_adjW(const float* __restrict__ adj,
                                              const float* __restrict__ sc_adj,
                                              float* __restrict__ W) {
    __shared__ float ta[16][NK + 1];
    __shared__ float tb[16][NK + 1];
    int b = blockIdx.z;
    int n0 = blockIdx.y * 16, n1 = blockIdx.x * 16;
    int tid = threadIdx.y * 16 + threadIdx.x;
    const float* adjb = adj + (size_t)b * NN * NK;
    const float* scb = sc_adj + b * NK;
    for (int i = tid; i < 16 * NK; i += 256) {
        int r = i / NK, j = i % NK;
        ta[r][j] = adjb[(n0 + r) * NK + j] * scb[j];
        tb[r][j] = adjb[(n1 + r) * NK + j];
    }
    __syncthreads();
    float s = 0.f;
    for (int j = 0; j < NK; j++) s += ta[threadIdx.y][j] * tb[threadIdx.x][j];
    W[(size_t)b * NM * NM + (size_t)(n0 + threadIdx.y) * NM + (n1 + threadIdx.x)] = s;
}

// ---- cross columns: each has exactly 5 ones (deg 5), 25-entry outer-product scatter ----
__global__ void k_scatter(const int* __restrict__ knn, const int* __restrict__ rev,
                          float* __restrict__ W) {
    int g = blockIdx.x * blockDim.x + threadIdx.x;  // b*NM + col
    if (g >= NB * NM) return;
    int b = g / NM, col = g % NM;
    const float cval = 1.0f / (5.0f + 1e-8f);
    int r[5];
    r[0] = col;
    if (col < NN) {
        const int* kk = knn + (size_t)(b * NN + col) * 4;
#pragma unroll
        for (int t = 0; t < 4; t++) r[t + 1] = NN + kk[t];
    } else {
        const int* rr = rev + (size_t)(b * NA + (col - NN)) * 4;
#pragma unroll
        for (int t = 0; t < 4; t++) r[t + 1] = rr[t];
    }
    float* Wb = W + (size_t)b * NM * NM;
#pragma unroll
    for (int i = 0; i < 5; i++)
#pragma unroll
        for (int j = 0; j < 5; j++) atomicAdd(&Wb[(size_t)r[i] * NM + r[j]], cval);
}

// ---- d_is[row] = 1/sqrt(rowsum(W) + 1 (identity) + eps); one wave per row ----
__global__ __launch_bounds__(256) void k_dis(const float* __restrict__ W, float* __restrict__ dis) {
    int wid = (blockIdx.x * 256 + threadIdx.x) >> 6;  // global row = b*NM + i
    int lane = threadIdx.x & 63;
    if (wid >= NB * NM) return;
    const float* row = W + (size_t)wid * NM;
    float s = 0.f;
    for (int t = lane; t < NM; t += 64) s += row[t];
    s = wave_reduce_add(s);
    if (lane == 0) dis[wid] = 1.0f / sqrtf(s + 1.0f + 1e-8f);
}

// ---- Y0 = joint_X^T  (M x C per batch), XhatT = 0.9 * Y0 ----
__global__ void k_y0(const float* __restrict__ feat, const float* __restrict__ tf,
                     float* __restrict__ Y0, float* __restrict__ XhatT) {
    int g = blockIdx.x, c = threadIdx.x;  // g = b*NM + m
    int b = g / NM, m = g % NM;
    float v = (m < NN) ? feat[((size_t)b * NC + c) * NN + m] : tf[(size_t)(m - NN) * NC + c];
    Y0[(size_t)g * NC + c] = v;
    XhatT[(size_t)g * NC + c] = 0.9f * v;
}

// ---- propagation: Yout = Amat @ Yin ; XhatT += coef * Yout
//      out[i,c] = dis[i]*( acc[i,c] + dis[i]*Yin[i,c] ),  acc = W @ (dis.*Yin)
__global__ __launch_bounds__(256) void k_prop(const float* __restrict__ W,
                                              const float* __restrict__ dis,
                                              const float* __restrict__ Yin,
                                              float* __restrict__ Yout,
                                              float* __restrict__ XhatT, float coef) {
    __shared__ float WtT[16][36];   // transposed W tile, stride 36 floats = 144B (16B-aligned)
    __shared__ float Zt[16][NC];
    int b = blockIdx.y;
    int i0 = blockIdx.x * 32;
    int tid = threadIdx.x;
    int tm = tid >> 5, tn = tid & 31;
    const float* Wb = W + ((size_t)b * NM + i0) * NM;
    const float* disb = dis + b * NM;
    const float* Yb = Yin + (size_t)b * NM * NC;
    float acc[4][4] = {{0.f}};
    for (int k0 = 0; k0 < NM; k0 += 16) {
#pragma unroll
        for (int it = 0; it < 2; it++) {
            int idx = tid + it * 256;
            int kr = idx >> 5, cc = (idx & 31) << 2;
            float4 yv = *(const float4*)&Yb[(size_t)(k0 + kr) * NC + cc];
            float dk = disb[k0 + kr];
            float4 zv; zv.x = yv.x * dk; zv.y = yv.y * dk; zv.z = yv.z * dk; zv.w = yv.w * dk;
            *(float4*)&Zt[kr][cc] = zv;
        }
        if (tid < 128) {
            int r = tid >> 2, c4 = (tid & 3) << 2;
            float4 wv = *(const float4*)&Wb[(size_t)r * NM + k0 + c4];
            WtT[c4 + 0][r] = wv.x; WtT[c4 + 1][r] = wv.y;
            WtT[c4 + 2][r] = wv.z; WtT[c4 + 3][r] = wv.w;
        }
        __syncthreads();
#pragma unroll
        for (int kk = 0; kk < 16; kk++) {
            float4 wv = *(const float4*)&WtT[kk][tm << 2];
            float4 zv = *(const float4*)&Zt[kk][tn << 2];
            acc[0][0] += wv.x * zv.x; acc[0][1] += wv.x * zv.y; acc[0][2] += wv.x * zv.z; acc[0][3] += wv.x * zv.w;
            acc[1][0] += wv.y * zv.x; acc[1][1] += wv.y * zv.y; acc[1][2] += wv.y * zv.z; acc[1][3] += wv.y * zv.w;
            acc[2][0] += wv.z * zv.x; acc[2][1] += wv.z * zv.y; acc[2][2] += wv.z * zv.z; acc[2][3] += wv.z * zv.w;
            acc[3][0] += wv.w * zv.x; acc[3][1] += wv.w * zv.y; acc[3][2] += wv.w * zv.z; acc[3][3] += wv.w * zv.w;
        }
        __syncthreads();
    }
    int ibase = i0 + (tm << 2);
    float* Youtb = Yout + (size_t)b * NM * NC;
    float* Xb = XhatT + (size_t)b * NM * NC;
#pragma unroll
    for (int r = 0; r < 4; r++) {
        int i = ibase + r;
        float di = disb[i];
        size_t off = (size_t)i * NC + (tn << 2);
        float4 yv = *(const float4*)&Yb[off];
        float4 o;
        o.x = di * (acc[r][0] + di * yv.x);
        o.y = di * (acc[r][1] + di * yv.y);
        o.z = di * (acc[r][2] + di * yv.z);
        o.w = di * (acc[r][3] + di * yv.w);
        *(float4*)&Youtb[off] = o;
        float4 xh = *(const float4*)&Xb[off];
        xh.x += coef * o.x; xh.y += coef * o.y; xh.z += coef * o.z; xh.w += coef * o.w;
        *(float4*)&Xb[off] = xh;
    }
}

// ---- write X_hat (B,C,N) from XhatT (B,M,C), n < N only ----
__global__ void k_xhat_out(const float* __restrict__ XhatT, float* __restrict__ out) {
    int bc = blockIdx.x;  // b*NC + c
    int b = bc / NC, c = bc % NC;
    int n = threadIdx.x;
    out[(size_t)bc * NN + n] = XhatT[((size_t)b * NM + n) * NC + c];
}

// ---- X_E[b,k,c] = inv_edge[b,k] * sum_n adj[b,n,k]*isn[b,n]*XhatT[b,n,c] ----
__global__ void k_xe(const float* __restrict__ adj, const float* __restrict__ isn,
                     const float* __restrict__ inv_edge, const float* __restrict__ XhatT,
                     float* __restrict__ outE) {
    int bk = blockIdx.x;  // b*NK + k
    int b = bk / NK, k = bk % NK;
    int c = threadIdx.x;
    float s = 0.f;
    for (int n = 0; n < NN; n++) {
        float av = adj[(size_t)(b * NN + n) * NK + k];
        if (av != 0.0f) s += av * isn[b * NN + n] * XhatT[((size_t)b * NM + n) * NC + c];
    }
    outE[(size_t)bk * NC + c] = inv_edge[bk] * s;
}

extern "C" void kernel_launch(void* const* d_in, const int* in_sizes, int n_in,
                              void* d_out, int out_size, void* d_ws, size_t ws_size,
                              hipStream_t stream) {
    (void)in_sizes; (void)n_in; (void)out_size; (void)ws_size;
    const float* features = (const float*)d_in[0];  // (B,C,N)
    const float* adj      = (const float*)d_in[1];  // (B,N,K)
    const float* tf       = (const float*)d_in[2];  // (A,C)
    const float* mem_adj  = (const float*)d_in[3];  // (A,K)
    float* out_xhat = (float*)d_out;                 // (B,C,N)
    float* out_xe   = out_xhat + (size_t)NB * NC * NN;  // (B,K,C)

    float* p = (float*)d_ws;
    float* memN_T  = p; p += (size_t)NC * NA;
    float* Xn      = p; p += (size_t)NB * NN * NC;
    float* sim     = p; p += (size_t)NB * NN * NA;
    float* sc_adj  = p; p += NB * NK;
    float* inv_edge= p; p += NB * NK;
    float* dmem_inv= p; p += NK;
    float* isn     = p; p += NB * NN;
    float* dis     = p; p += NB * NM;
    float* W       = p; p += (size_t)NB * NM * NM;
    float* Y0      = p; p += (size_t)NB * NM * NC;
    float* Y1      = p; p += (size_t)NB * NM * NC;
    float* XhatT   = p; p += (size_t)NB * NM * NC;
    int* knn = (int*)p;
    int* rev = knn + NB * NN * 4;

    hipMemsetAsync(W, 0, sizeof(float) * (size_t)NB * NM * NM, stream);
    k_norm_mem<<<NA, NC, 0, stream>>>(tf, memN_T);
    k_norm_x<<<NB * NN, NC, 0, stream>>>(features, Xn);
    k_dmem<<<1, 128, 0, stream>>>(mem_adj, dmem_inv);
    k_adj_deg<<<NB, 256, 0, stream>>>(adj, sc_adj, inv_edge, isn);
    k_sim<<<NB * NN / 8, 512, 0, stream>>>(Xn, memN_T, sim);
    k_knn<<<NB * NN / 4, 256, 0, stream>>>(sim, knn);
    k_rev<<<NB * NA / 4, 256, 0, stream>>>(sim, rev);
    k_memW<<<dim3(NA / 16, NA / 16), dim3(16, 16), 0, stream>>>(mem_adj, dmem_inv, W);
    k_adjW<<<dim3(NN / 16, NN / 16, NB), dim3(16, 16), 0, stream>>>(adj, sc_adj, W);
    k_scatter<<<NB * NM / 256, 256, 0, stream>>>(knn, rev, W);
    k_dis<<<NB * NM / 4, 256, 0, stream>>>(W, dis);
    k_y0<<<NB * NM, NC, 0, stream>>>(features, tf, Y0, XhatT);
    dim3 pg(NM / 32, NB);
    k_prop<<<pg, 256, 0, stream>>>(W, dis, Y0, Y1, XhatT, 0.09f);
    k_prop<<<pg, 256, 0, stream>>>(W, dis, Y1, Y0, XhatT, 0.009f);
    k_prop<<<pg, 256, 0, stream>>>(W, dis, Y0, Y1, XhatT, 0.001f);
    k_xhat_out<<<NB * NC, NN, 0, stream>>>(XhatT, out_xhat);
    k_xe<<<NB * NK, NC, 0, stream>>>(adj, isn, inv_edge, XhatT, out_xe);
}

// Round 3
// 281.169 us; speedup vs baseline: 2.8968x; 1.2287x over previous
//
#include <hip/hip_runtime.h>

#define NB 8
#define NC 128
#define NN 256
#define NK 96
#define NA 512
#define NM 768   // NN + NA

__device__ __forceinline__ float wave_reduce_add(float s) {
    for (int o = 32; o > 0; o >>= 1) s += __shfl_down(s, o, 64);
    return s;
}

// ---- normalize memory features, store transposed (C, A) for coalesced sim ----
__global__ void k_norm_mem(const float* __restrict__ tf, float* __restrict__ memN_T) {
    int a = blockIdx.x, c = threadIdx.x;
    float v = tf[a * NC + c];
    float s = wave_reduce_add(v * v);
    __shared__ float p[2];
    if ((threadIdx.x & 63) == 0) p[threadIdx.x >> 6] = s;
    __syncthreads();
    float norm = sqrtf(p[0] + p[1]);
    memN_T[c * NA + a] = v / fmaxf(norm, 1e-12f);
}

// ---- normalize test features per (b,n) over C, store (B*N, C) ----
__global__ void k_norm_x(const float* __restrict__ feat, float* __restrict__ Xn) {
    int g = blockIdx.x, c = threadIdx.x;   // g = b*NN + n
    int b = g >> 8, n = g & 255;
    float v = feat[(b * NC + c) * NN + n];
    float s = wave_reduce_add(v * v);
    __shared__ float p[2];
    if ((threadIdx.x & 63) == 0) p[threadIdx.x >> 6] = s;
    __syncthreads();
    float norm = sqrtf(p[0] + p[1]);
    Xn[g * NC + c] = v / fmaxf(norm, 1e-12f);
}

// ---- memory hyperedge degrees: one wave per j ----
__global__ __launch_bounds__(256) void k_dmem(const float* __restrict__ mem_adj,
                                              float* __restrict__ dmem_inv) {
    int wid = (blockIdx.x * 256 + threadIdx.x) >> 6;  // j
    int lane = threadIdx.x & 63;
    if (wid >= NK) return;
    float s = 0.f;
    for (int a = lane; a < NA; a += 64) s += mem_adj[(size_t)a * NK + wid];
    s = wave_reduce_add(s);
    if (lane == 0) dmem_inv[wid] = 1.0f / (s + 1e-8f);
}

// ---- adj hyperedge (column) degrees: one wave per (b,k) ----
__global__ __launch_bounds__(256) void k_edge_deg(const float* __restrict__ adj,
                                                  float* __restrict__ sc_adj,
                                                  float* __restrict__ inv_edge) {
    int wid = (blockIdx.x * 256 + threadIdx.x) >> 6;  // b*NK + k
    int lane = threadIdx.x & 63;
    if (wid >= NB * NK) return;
    int b = wid / NK, k = wid % NK;
    float s = 0.f;
    for (int n = lane; n < NN; n += 64) s += adj[(size_t)(b * NN + n) * NK + k];
    s = wave_reduce_add(s);
    if (lane == 0) {
        sc_adj[wid] = 1.0f / (s + 1e-8f);
        inv_edge[wid] = 1.0f / fmaxf(s, 1e-8f);
    }
}

// ---- node degrees: one wave per (b,n), row is 96 contiguous floats ----
__global__ __launch_bounds__(256) void k_node_deg(const float* __restrict__ adj,
                                                   float* __restrict__ isn) {
    int wid = (blockIdx.x * 256 + threadIdx.x) >> 6;  // b*NN + n
    int lane = threadIdx.x & 63;
    if (wid >= NB * NN) return;
    const float* row = adj + (size_t)wid * NK;
    float s = (lane < NK) ? row[lane] : 0.f;
    if (lane + 64 < NK) s += row[lane + 64];
    s = wave_reduce_add(s);
    if (lane == 0) isn[wid] = 1.0f / sqrtf(fmaxf(s, 1e-8f));
}

// ---- cosine similarity sim[b*N+n][a] = <Xn_row, memN_col> ----
__global__ __launch_bounds__(512) void k_sim(const float* __restrict__ Xn,
                                             const float* __restrict__ memN_T,
                                             float* __restrict__ sim) {
    __shared__ float xr[8][NC];
    int g0 = blockIdx.x * 8;
    int t = threadIdx.x;
    for (int i = t; i < 8 * NC; i += 512) xr[i / NC][i % NC] = Xn[g0 * NC + i];
    __syncthreads();
    float acc[8] = {0, 0, 0, 0, 0, 0, 0, 0};
    int a = t;  // 0..511
    for (int c = 0; c < NC; c++) {
        float m = memN_T[c * NA + a];
#pragma unroll
        for (int r = 0; r < 8; r++) acc[r] += xr[r][c] * m;
    }
#pragma unroll
    for (int r = 0; r < 8; r++) sim[(size_t)(g0 + r) * NA + a] = acc[r];
}

// ---- sortable key: higher value wins, tie -> lower index (== lax.top_k order) ----
__device__ __forceinline__ unsigned long long pack_key(float v, unsigned idx) {
    unsigned u = __float_as_uint(v);
    u = (u & 0x80000000u) ? ~u : (u | 0x80000000u);
    return ((unsigned long long)u << 32) | (unsigned long long)(0xFFFFFFFFu - idx);
}

__device__ __forceinline__ void ins4(unsigned long long v, unsigned long long* k) {
    if (v > k[3]) {
        if (v > k[1]) {
            if (v > k[0]) { k[3] = k[2]; k[2] = k[1]; k[1] = k[0]; k[0] = v; }
            else         { k[3] = k[2]; k[2] = k[1]; k[1] = v; }
        } else {
            if (v > k[2]) { k[3] = k[2]; k[2] = v; }
            else          { k[3] = v; }
        }
    }
}

// butterfly merge of per-lane sorted-desc top-4 lists -> global top-4 in every lane
__device__ __forceinline__ void merge_top4(unsigned long long* k) {
#pragma unroll
    for (int d = 1; d < 64; d <<= 1) {
        unsigned long long p0 = __shfl_xor(k[0], d, 64);
        unsigned long long p1 = __shfl_xor(k[1], d, 64);
        unsigned long long p2 = __shfl_xor(k[2], d, 64);
        unsigned long long p3 = __shfl_xor(k[3], d, 64);
        unsigned long long c0 = k[0] > p3 ? k[0] : p3;
        unsigned long long c1 = k[1] > p2 ? k[1] : p2;
        unsigned long long c2 = k[2] > p1 ? k[2] : p1;
        unsigned long long c3 = k[3] > p0 ? k[3] : p0;
        unsigned long long d0 = c0 > c2 ? c0 : c2, d2 = c0 > c2 ? c2 : c0;
        unsigned long long d1 = c1 > c3 ? c1 : c3, d3 = c1 > c3 ? c3 : c1;
        k[0] = d0 > d1 ? d0 : d1; k[1] = d0 > d1 ? d1 : d0;
        k[2] = d2 > d3 ? d2 : d3; k[3] = d2 > d3 ? d3 : d2;
    }
}

// ---- top-4 memory neighbors per test node: one wave per (b,n) row ----
__global__ __launch_bounds__(256) void k_knn(const float* __restrict__ sim, int* __restrict__ knn) {
    int wid = (blockIdx.x * 256 + threadIdx.x) >> 6;  // b*NN + n
    int lane = threadIdx.x & 63;
    if (wid >= NB * NN) return;
    const float* row = sim + (size_t)wid * NA;
    unsigned long long k[4] = {0, 0, 0, 0};
#pragma unroll
    for (int t = 0; t < NA / 64; t++) {
        int a = lane + 64 * t;
        ins4(pack_key(row[a], (unsigned)a), k);
    }
    merge_top4(k);
    if (lane < 4) knn[wid * 4 + lane] = (int)(0xFFFFFFFFu - (unsigned)k[lane]);
}

// ---- top-4 test neighbors per memory node: one wave per (b,a) column ----
__global__ __launch_bounds__(256) void k_rev(const float* __restrict__ sim, int* __restrict__ rev) {
    int wid = (blockIdx.x * 256 + threadIdx.x) >> 6;  // b*NA + a
    int lane = threadIdx.x & 63;
    if (wid >= NB * NA) return;
    int b = wid >> 9, a = wid & 511;
    const float* base = sim + (size_t)b * NN * NA + a;
    unsigned long long k[4] = {0, 0, 0, 0};
#pragma unroll
    for (int t = 0; t < NN / 64; t++) {
        int n = lane + 64 * t;
        ins4(pack_key(base[(size_t)n * NA], (unsigned)n), k);
    }
    merge_top4(k);
    if (lane < 4) rev[wid * 4 + lane] = (int)(0xFFFFFFFFu - (unsigned)k[lane]);
}

// ---- bottom-right A x A block of W (batch-independent), written to all batches ----
__global__ __launch_bounds__(256) void k_memW(const float* __restrict__ mem_adj,
                                              const float* __restrict__ dmem_inv,
                                              float* __restrict__ W) {
    __shared__ float ta[16][NK + 1];
    __shared__ float tb[16][NK + 1];
    int a0 = blockIdx.y * 16, a1 = blockIdx.x * 16;
    int tid = threadIdx.y * 16 + threadIdx.x;
    for (int i = tid; i < 16 * NK; i += 256) {
        int r = i / NK, j = i % NK;
        ta[r][j] = mem_adj[(a0 + r) * NK + j] * dmem_inv[j];
        tb[r][j] = mem_adj[(a1 + r) * NK + j];
    }
    __syncthreads();
    float s = 0.f;
    for (int j = 0; j < NK; j++) s += ta[threadIdx.y][j] * tb[threadIdx.x][j];
    int row = NN + a0 + threadIdx.y, col = NN + a1 + threadIdx.x;
    for (int b = 0; b < NB; b++) W[(size_t)b * NM * NM + (size_t)row * NM + col] = s;
}

// ---- top-left N x N block of W per batch ----
__global__ __launch_bounds__(256) void k_adjW(const float* __restrict__ adj,
                                              const float* __restrict__ sc_adj,
                                              float* __restrict__ W) {
    __shared__ float ta[16][NK + 1];
    __shared__ float tb[16][NK + 1];
    int b = blockIdx.z;
    int n0 = blockIdx.y * 16, n1 = blockIdx.x * 16;
    int tid = threadIdx.y * 16 + threadIdx.x;
    const float* adjb = adj + (size_t)b * NN * NK;
    const float* scb = sc_adj + b * NK;
    for (int i = tid; i < 16 * NK; i += 256) {
        int r = i / NK, j = i % NK;
        ta[r][j] = adjb[(n0 + r) * NK + j] * scb[j];
        tb[r][j] = adjb[(n1 + r) * NK + j];
    }
    __syncthreads();
    float s = 0.f;
    for (int j = 0; j < NK; j++) s += ta[threadIdx.y][j] * tb[threadIdx.x][j];
    W[(size_t)b * NM * NM + (size_t)(n0 + threadIdx.y) * NM + (n1 + threadIdx.x)] = s;
}

// ---- cross columns: each has exactly 5 ones (deg 5), 25-entry outer-product scatter ----
__global__ void k_scatter(const int* __restrict__ knn, const int* __restrict__ rev,
                          float* __restrict__ W) {
    int g = blockIdx.x * blockDim.x + threadIdx.x;  // b*NM + col
    if (g >= NB * NM) return;
    int b = g / NM, col = g % NM;
    const float cval = 1.0f / (5.0f + 1e-8f);
    int r[5];
    r[0] = col;
    if (col < NN) {
        const int* kk = knn + (size_t)(b * NN + col) * 4;
#pragma unroll
        for (int t = 0; t < 4; t++) r[t + 1] = NN + kk[t];
    } else {
        const int* rr = rev + (size_t)(b * NA + (col - NN)) * 4;
#pragma unroll
        for (int t = 0; t < 4; t++) r[t + 1] = rr[t];
    }
    float* Wb = W + (size_t)b * NM * NM;
#pragma unroll
    for (int i = 0; i < 5; i++)
#pragma unroll
        for (int j = 0; j < 5; j++) atomicAdd(&Wb[(size_t)r[i] * NM + r[j]], cval);
}

// ---- d_is[row] = 1/sqrt(rowsum(W) + 1 (identity) + eps); one wave per row ----
__global__ __launch_bounds__(256) void k_dis(const float* __restrict__ W, float* __restrict__ dis) {
    int wid = (blockIdx.x * 256 + threadIdx.x) >> 6;  // global row = b*NM + i
    int lane = threadIdx.x & 63;
    if (wid >= NB * NM) return;
    const float* row = W + (size_t)wid * NM;
    float s = 0.f;
    for (int t = lane; t < NM; t += 64) s += row[t];
    s = wave_reduce_add(s);
    if (lane == 0) dis[wid] = 1.0f / sqrtf(s + 1.0f + 1e-8f);
}

// ---- Y0 = joint_X^T  (M x C per batch), XhatT = 0.9 * Y0 ----
__global__ void k_y0(const float* __restrict__ feat, const float* __restrict__ tf,
                     float* __restrict__ Y0, float* __restrict__ XhatT) {
    int g = blockIdx.x, c = threadIdx.x;  // g = b*NM + m
    int b = g / NM, m = g % NM;
    float v = (m < NN) ? feat[((size_t)b * NC + c) * NN + m] : tf[(size_t)(m - NN) * NC + c];
    Y0[(size_t)g * NC + c] = v;
    XhatT[(size_t)g * NC + c] = 0.9f * v;
}

// ---- propagation: Yout = Amat @ Yin ; XhatT += coef * Yout
//      out[i,c] = dis[i]*( acc[i,c] + dis[i]*Yin[i,c] ),  acc = W @ (dis.*Yin)
__global__ __launch_bounds__(256) void k_prop(const float* __restrict__ W,
                                              const float* __restrict__ dis,
                                              const float* __restrict__ Yin,
                                              float* __restrict__ Yout,
                                              float* __restrict__ XhatT, float coef) {
    __shared__ float WtT[16][36];   // transposed W tile, stride 36 floats = 144B (16B-aligned)
    __shared__ float Zt[16][NC];
    int b = blockIdx.y;
    int i0 = blockIdx.x * 32;
    int tid = threadIdx.x;
    int tm = tid >> 5, tn = tid & 31;
    const float* Wb = W + ((size_t)b * NM + i0) * NM;
    const float* disb = dis + b * NM;
    const float* Yb = Yin + (size_t)b * NM * NC;
    float acc[4][4] = {{0.f}};
    for (int k0 = 0; k0 < NM; k0 += 16) {
#pragma unroll
        for (int it = 0; it < 2; it++) {
            int idx = tid + it * 256;
            int kr = idx >> 5, cc = (idx & 31) << 2;
            float4 yv = *(const float4*)&Yb[(size_t)(k0 + kr) * NC + cc];
            float dk = disb[k0 + kr];
            float4 zv; zv.x = yv.x * dk; zv.y = yv.y * dk; zv.z = yv.z * dk; zv.w = yv.w * dk;
            *(float4*)&Zt[kr][cc] = zv;
        }
        if (tid < 128) {
            int r = tid >> 2, c4 = (tid & 3) << 2;
            float4 wv = *(const float4*)&Wb[(size_t)r * NM + k0 + c4];
            WtT[c4 + 0][r] = wv.x; WtT[c4 + 1][r] = wv.y;
            WtT[c4 + 2][r] = wv.z; WtT[c4 + 3][r] = wv.w;
        }
        __syncthreads();
#pragma unroll
        for (int kk = 0; kk < 16; kk++) {
            float4 wv = *(const float4*)&WtT[kk][tm << 2];
            float4 zv = *(const float4*)&Zt[kk][tn << 2];
            acc[0][0] += wv.x * zv.x; acc[0][1] += wv.x * zv.y; acc[0][2] += wv.x * zv.z; acc[0][3] += wv.x * zv.w;
            acc[1][0] += wv.y * zv.x; acc[1][1] += wv.y * zv.y; acc[1][2] += wv.y * zv.z; acc[1][3] += wv.y * zv.w;
            acc[2][0] += wv.z * zv.x; acc[2][1] += wv.z * zv.y; acc[2][2] += wv.z * zv.z; acc[2][3] += wv.z * zv.w;
            acc[3][0] += wv.w * zv.x; acc[3][1] += wv.w * zv.y; acc[3][2] += wv.w * zv.z; acc[3][3] += wv.w * zv.w;
        }
        __syncthreads();
    }
    int ibase = i0 + (tm << 2);
    float* Youtb = Yout + (size_t)b * NM * NC;
    float* Xb = XhatT + (size_t)b * NM * NC;
#pragma unroll
    for (int r = 0; r < 4; r++) {
        int i = ibase + r;
        float di = disb[i];
        size_t off = (size_t)i * NC + (tn << 2);
        float4 yv = *(const float4*)&Yb[off];
        float4 o;
        o.x = di * (acc[r][0] + di * yv.x);
        o.y = di * (acc[r][1] + di * yv.y);
        o.z = di * (acc[r][2] + di * yv.z);
        o.w = di * (acc[r][3] + di * yv.w);
        *(float4*)&Youtb[off] = o;
        float4 xh = *(const float4*)&Xb[off];
        xh.x += coef * o.x; xh.y += coef * o.y; xh.z += coef * o.z; xh.w += coef * o.w;
        *(float4*)&Xb[off] = xh;
    }
}

// ---- write X_hat (B,C,N) from XhatT (B,M,C), n < N only ----
__global__ void k_xhat_out(const float* __restrict__ XhatT, float* __restrict__ out) {
    int bc = blockIdx.x;  // b*NC + c
    int b = bc / NC, c = bc % NC;
    int n = threadIdx.x;
    out[(size_t)bc * NN + n] = XhatT[((size_t)b * NM + n) * NC + c];
}

// ---- X_E as tiled GEMM: X_E[b,k,c] = inv_edge[b,k] * sum_n (adj[b,n,k]*isn[b,n]) * XhatT[b,n,c]
__global__ __launch_bounds__(256) void k_xe(const float* __restrict__ adj,
                                            const float* __restrict__ isn,
                                            const float* __restrict__ inv_edge,
                                            const float* __restrict__ XhatT,
                                            float* __restrict__ outE) {
    __shared__ float ta[16][17];  // [n_local][k_local]
    __shared__ float tz[16][17];  // [n_local][c_local]
    int b = blockIdx.z;
    int k0 = blockIdx.y * 16;  // 6 tiles
    int c0 = blockIdx.x * 16;  // 8 tiles
    int tx = threadIdx.x & 15;
    int ty = threadIdx.x >> 4;
    float acc = 0.f;
    for (int n0 = 0; n0 < NN; n0 += 16) {
        int n = n0 + ty;
        ta[ty][tx] = adj[(size_t)(b * NN + n) * NK + k0 + tx] * isn[b * NN + n];
        tz[ty][tx] = XhatT[(size_t)(b * NM + n) * NC + c0 + tx];
        __syncthreads();
#pragma unroll
        for (int nn = 0; nn < 16; nn++) acc += ta[nn][ty] * tz[nn][tx];
        __syncthreads();
    }
    int k = k0 + ty, c = c0 + tx;
    outE[(size_t)(b * NK + k) * NC + c] = inv_edge[b * NK + k] * acc;
}

extern "C" void kernel_launch(void* const* d_in, const int* in_sizes, int n_in,
                              void* d_out, int out_size, void* d_ws, size_t ws_size,
                              hipStream_t stream) {
    (void)in_sizes; (void)n_in; (void)out_size; (void)ws_size;
    const float* features = (const float*)d_in[0];  // (B,C,N)
    const float* adj      = (const float*)d_in[1];  // (B,N,K)
    const float* tf       = (const float*)d_in[2];  // (A,C)
    const float* mem_adj  = (const float*)d_in[3];  // (A,K)
    float* out_xhat = (float*)d_out;                 // (B,C,N)
    float* out_xe   = out_xhat + (size_t)NB * NC * NN;  // (B,K,C)

    float* p = (float*)d_ws;
    float* memN_T  = p; p += (size_t)NC * NA;
    float* Xn      = p; p += (size_t)NB * NN * NC;
    float* sim     = p; p += (size_t)NB * NN * NA;
    float* sc_adj  = p; p += NB * NK;
    float* inv_edge= p; p += NB * NK;
    float* dmem_inv= p; p += NK;
    float* isn     = p; p += NB * NN;
    float* dis     = p; p += NB * NM;
    float* W       = p; p += (size_t)NB * NM * NM;
    float* Y0      = p; p += (size_t)NB * NM * NC;
    float* Y1      = p; p += (size_t)NB * NM * NC;
    float* XhatT   = p; p += (size_t)NB * NM * NC;
    int* knn = (int*)p;
    int* rev = knn + NB * NN * 4;

    hipMemsetAsync(W, 0, sizeof(float) * (size_t)NB * NM * NM, stream);
    k_norm_mem<<<NA, NC, 0, stream>>>(tf, memN_T);
    k_norm_x<<<NB * NN, NC, 0, stream>>>(features, Xn);
    k_dmem<<<(NK * 64 + 255) / 256, 256, 0, stream>>>(mem_adj, dmem_inv);
    k_edge_deg<<<NB * NK / 4, 256, 0, stream>>>(adj, sc_adj, inv_edge);
    k_node_deg<<<NB * NN / 4, 256, 0, stream>>>(adj, isn);
    k_sim<<<NB * NN / 8, 512, 0, stream>>>(Xn, memN_T, sim);
    k_knn<<<NB * NN / 4, 256, 0, stream>>>(sim, knn);
    k_rev<<<NB * NA / 4, 256, 0, stream>>>(sim, rev);
    k_memW<<<dim3(NA / 16, NA / 16), dim3(16, 16), 0, stream>>>(mem_adj, dmem_inv, W);
    k_adjW<<<dim3(NN / 16, NN / 16, NB), dim3(16, 16), 0, stream>>>(adj, sc_adj, W);
    k_scatter<<<NB * NM / 256, 256, 0, stream>>>(knn, rev, W);
    k_dis<<<NB * NM / 4, 256, 0, stream>>>(W, dis);
    k_y0<<<NB * NM, NC, 0, stream>>>(features, tf, Y0, XhatT);
    dim3 pg(NM / 32, NB);
    k_prop<<<pg, 256, 0, stream>>>(W, dis, Y0, Y1, XhatT, 0.09f);
    k_prop<<<pg, 256, 0, stream>>>(W, dis, Y1, Y0, XhatT, 0.009f);
    k_prop<<<pg, 256, 0, stream>>>(W, dis, Y0, Y1, XhatT, 0.001f);
    k_xhat_out<<<NB * NC, NN, 0, stream>>>(XhatT, out_xhat);
    k_xe<<<dim3(NC / 16, NK / 16, NB), 256, 0, stream>>>(adj, isn, inv_edge, XhatT, out_xe);
}

// Round 4
// 163.795 us; speedup vs baseline: 4.9726x; 1.7166x over previous
//
#include <hip/hip_runtime.h>

#define NB 8
#define NC 128
#define NN 256
#define NK 96
#define NA 512
#define NM 768   // NN + NA

typedef __attribute__((ext_vector_type(8))) short bf16x8;
typedef __attribute__((ext_vector_type(4))) float f32x4;
typedef __attribute__((ext_vector_type(4))) unsigned short u16x4;

__device__ __forceinline__ float wave_reduce_add(float s) {
    for (int o = 32; o > 0; o >>= 1) s += __shfl_down(s, o, 64);
    return s;
}

// f32 -> bf16 round-to-nearest-even
__device__ __forceinline__ unsigned short f2bf(float x) {
    unsigned u = __float_as_uint(x);
    unsigned r = (u + 0x7FFFu + ((u >> 16) & 1u)) >> 16;
    return (unsigned short)r;
}
__device__ __forceinline__ float bf2f(unsigned short h) {
    return __uint_as_float((unsigned)h << 16);
}

// ---- normalize memory features -> memN_T (C,A); also raw transpose tfT (C,A) ----
__global__ void k_norm_mem(const float* __restrict__ tf, float* __restrict__ memN_T,
                           float* __restrict__ tfT) {
    int a = blockIdx.x, c = threadIdx.x;
    float v = tf[a * NC + c];
    float s = wave_reduce_add(v * v);
    __shared__ float p[2];
    if ((threadIdx.x & 63) == 0) p[threadIdx.x >> 6] = s;
    __syncthreads();
    float norm = sqrtf(p[0] + p[1]);
    memN_T[c * NA + a] = v / fmaxf(norm, 1e-12f);
    tfT[c * NA + a] = v;
}

// ---- normalize test features per (b,n) over C, store (B*N, C) ----
__global__ void k_norm_x(const float* __restrict__ feat, float* __restrict__ Xn) {
    int g = blockIdx.x, c = threadIdx.x;   // g = b*NN + n
    int b = g >> 8, n = g & 255;
    float v = feat[(b * NC + c) * NN + n];
    float s = wave_reduce_add(v * v);
    __shared__ float p[2];
    if ((threadIdx.x & 63) == 0) p[threadIdx.x >> 6] = s;
    __syncthreads();
    float norm = sqrtf(p[0] + p[1]);
    Xn[g * NC + c] = v / fmaxf(norm, 1e-12f);
}

// ---- memory hyperedge degrees: one wave per j ----
__global__ __launch_bounds__(256) void k_dmem(const float* __restrict__ mem_adj,
                                              float* __restrict__ dmem_inv) {
    int wid = (blockIdx.x * 256 + threadIdx.x) >> 6;  // j
    int lane = threadIdx.x & 63;
    if (wid >= NK) return;
    float s = 0.f;
    for (int a = lane; a < NA; a += 64) s += mem_adj[(size_t)a * NK + wid];
    s = wave_reduce_add(s);
    if (lane == 0) dmem_inv[wid] = 1.0f / (s + 1e-8f);
}

// ---- adj hyperedge (column) degrees: one wave per (b,k) ----
__global__ __launch_bounds__(256) void k_edge_deg(const float* __restrict__ adj,
                                                  float* __restrict__ sc_adj,
                                                  float* __restrict__ inv_edge) {
    int wid = (blockIdx.x * 256 + threadIdx.x) >> 6;  // b*NK + k
    int lane = threadIdx.x & 63;
    if (wid >= NB * NK) return;
    int b = wid / NK, k = wid % NK;
    float s = 0.f;
    for (int n = lane; n < NN; n += 64) s += adj[(size_t)(b * NN + n) * NK + k];
    s = wave_reduce_add(s);
    if (lane == 0) {
        sc_adj[wid] = 1.0f / (s + 1e-8f);
        inv_edge[wid] = 1.0f / fmaxf(s, 1e-8f);
    }
}

// ---- node degrees: one wave per (b,n), row is 96 contiguous floats ----
__global__ __launch_bounds__(256) void k_node_deg(const float* __restrict__ adj,
                                                   float* __restrict__ isn) {
    int wid = (blockIdx.x * 256 + threadIdx.x) >> 6;  // b*NN + n
    int lane = threadIdx.x & 63;
    if (wid >= NB * NN) return;
    const float* row = adj + (size_t)wid * NK;
    float s = (lane < NK) ? row[lane] : 0.f;
    if (lane + 64 < NK) s += row[lane + 64];
    s = wave_reduce_add(s);
    if (lane == 0) isn[wid] = 1.0f / sqrtf(fmaxf(s, 1e-8f));
}

// ---- cosine similarity sim[b*N+n][a] = <Xn_row, memN_col> ----
__global__ __launch_bounds__(512) void k_sim(const float* __restrict__ Xn,
                                             const float* __restrict__ memN_T,
                                             float* __restrict__ sim) {
    __shared__ float xr[8][NC];
    int g0 = blockIdx.x * 8;
    int t = threadIdx.x;
    for (int i = t; i < 8 * NC; i += 512) xr[i / NC][i % NC] = Xn[g0 * NC + i];
    __syncthreads();
    float acc[8] = {0, 0, 0, 0, 0, 0, 0, 0};
    int a = t;  // 0..511
    for (int c = 0; c < NC; c++) {
        float m = memN_T[c * NA + a];
#pragma unroll
        for (int r = 0; r < 8; r++) acc[r] += xr[r][c] * m;
    }
#pragma unroll
    for (int r = 0; r < 8; r++) sim[(size_t)(g0 + r) * NA + a] = acc[r];
}

// ---- sortable key: higher value wins, tie -> lower index (== lax.top_k order) ----
__device__ __forceinline__ unsigned long long pack_key(float v, unsigned idx) {
    unsigned u = __float_as_uint(v);
    u = (u & 0x80000000u) ? ~u : (u | 0x80000000u);
    return ((unsigned long long)u << 32) | (unsigned long long)(0xFFFFFFFFu - idx);
}

__device__ __forceinline__ void ins4(unsigned long long v, unsigned long long* k) {
    if (v > k[3]) {
        if (v > k[1]) {
            if (v > k[0]) { k[3] = k[2]; k[2] = k[1]; k[1] = k[0]; k[0] = v; }
            else         { k[3] = k[2]; k[2] = k[1]; k[1] = v; }
        } else {
            if (v > k[2]) { k[3] = k[2]; k[2] = v; }
            else          { k[3] = v; }
        }
    }
}

// butterfly merge of per-lane sorted-desc top-4 lists -> global top-4 in every lane
__device__ __forceinline__ void merge_top4(unsigned long long* k) {
#pragma unroll
    for (int d = 1; d < 64; d <<= 1) {
        unsigned long long p0 = __shfl_xor(k[0], d, 64);
        unsigned long long p1 = __shfl_xor(k[1], d, 64);
        unsigned long long p2 = __shfl_xor(k[2], d, 64);
        unsigned long long p3 = __shfl_xor(k[3], d, 64);
        unsigned long long c0 = k[0] > p3 ? k[0] : p3;
        unsigned long long c1 = k[1] > p2 ? k[1] : p2;
        unsigned long long c2 = k[2] > p1 ? k[2] : p1;
        unsigned long long c3 = k[3] > p0 ? k[3] : p0;
        unsigned long long d0 = c0 > c2 ? c0 : c2, d2 = c0 > c2 ? c2 : c0;
        unsigned long long d1 = c1 > c3 ? c1 : c3, d3 = c1 > c3 ? c3 : c1;
        k[0] = d0 > d1 ? d0 : d1; k[1] = d0 > d1 ? d1 : d0;
        k[2] = d2 > d3 ? d2 : d3; k[3] = d2 > d3 ? d3 : d2;
    }
}

// ---- top-4 memory neighbors per test node: one wave per (b,n) row ----
__global__ __launch_bounds__(256) void k_knn(const float* __restrict__ sim, int* __restrict__ knn) {
    int wid = (blockIdx.x * 256 + threadIdx.x) >> 6;  // b*NN + n
    int lane = threadIdx.x & 63;
    if (wid >= NB * NN) return;
    const float* row = sim + (size_t)wid * NA;
    unsigned long long k[4] = {0, 0, 0, 0};
#pragma unroll
    for (int t = 0; t < NA / 64; t++) {
        int a = lane + 64 * t;
        ins4(pack_key(row[a], (unsigned)a), k);
    }
    merge_top4(k);
    if (lane < 4) knn[wid * 4 + lane] = (int)(0xFFFFFFFFu - (unsigned)k[lane]);
}

// ---- top-4 test neighbors per memory node: one wave per (b,a) column ----
__global__ __launch_bounds__(256) void k_rev(const float* __restrict__ sim, int* __restrict__ rev) {
    int wid = (blockIdx.x * 256 + threadIdx.x) >> 6;  // b*NA + a
    int lane = threadIdx.x & 63;
    if (wid >= NB * NA) return;
    int b = wid >> 9, a = wid & 511;
    const float* base = sim + (size_t)b * NN * NA + a;
    unsigned long long k[4] = {0, 0, 0, 0};
#pragma unroll
    for (int t = 0; t < NN / 64; t++) {
        int n = lane + 64 * t;
        ins4(pack_key(base[(size_t)n * NA], (unsigned)n), k);
    }
    merge_top4(k);
    if (lane < 4) rev[wid * 4 + lane] = (int)(0xFFFFFFFFu - (unsigned)k[lane]);
}

// ---- bottom-right A x A block of W (batch-independent), written to all batches ----
__global__ __launch_bounds__(256) void k_memW(const float* __restrict__ mem_adj,
                                              const float* __restrict__ dmem_inv,
                                              float* __restrict__ W) {
    __shared__ float ta[16][NK + 1];
    __shared__ float tb[16][NK + 1];
    int a0 = blockIdx.y * 16, a1 = blockIdx.x * 16;
    int tid = threadIdx.y * 16 + threadIdx.x;
    for (int i = tid; i < 16 * NK; i += 256) {
        int r = i / NK, j = i % NK;
        ta[r][j] = mem_adj[(a0 + r) * NK + j] * dmem_inv[j];
        tb[r][j] = mem_adj[(a1 + r) * NK + j];
    }
    __syncthreads();
    float s = 0.f;
    for (int j = 0; j < NK; j++) s += ta[threadIdx.y][j] * tb[threadIdx.x][j];
    int row = NN + a0 + threadIdx.y, col = NN + a1 + threadIdx.x;
    for (int b = 0; b < NB; b++) W[(size_t)b * NM * NM + (size_t)row * NM + col] = s;
}

// ---- top-left N x N block of W per batch ----
__global__ __launch_bounds__(256) void k_adjW(const float* __restrict__ adj,
                                              const float* __restrict__ sc_adj,
                                              float* __restrict__ W) {
    __shared__ float ta[16][NK + 1];
    __shared__ float tb[16][NK + 1];
    int b = blockIdx.z;
    int n0 = blockIdx.y * 16, n1 = blockIdx.x * 16;
    int tid = threadIdx.y * 16 + threadIdx.x;
    const float* adjb = adj + (size_t)b * NN * NK;
    const float* scb = sc_adj + b * NK;
    for (int i = tid; i < 16 * NK; i += 256) {
        int r = i / NK, j = i % NK;
        ta[r][j] = adjb[(n0 + r) * NK + j] * scb[j];
        tb[r][j] = adjb[(n1 + r) * NK + j];
    }
    __syncthreads();
    float s = 0.f;
    for (int j = 0; j < NK; j++) s += ta[threadIdx.y][j] * tb[threadIdx.x][j];
    W[(size_t)b * NM * NM + (size_t)(n0 + threadIdx.y) * NM + (n1 + threadIdx.x)] = s;
}

// ---- cross columns: each has exactly 5 ones (deg 5), 25-entry outer-product scatter ----
__global__ void k_scatter(const int* __restrict__ knn, const int* __restrict__ rev,
                          float* __restrict__ W) {
    int g = blockIdx.x * blockDim.x + threadIdx.x;  // b*NM + col
    if (g >= NB * NM) return;
    int b = g / NM, col = g % NM;
    const float cval = 1.0f / (5.0f + 1e-8f);
    int r[5];
    r[0] = col;
    if (col < NN) {
        const int* kk = knn + (size_t)(b * NN + col) * 4;
#pragma unroll
        for (int t = 0; t < 4; t++) r[t + 1] = NN + kk[t];
    } else {
        const int* rr = rev + (size_t)(b * NA + (col - NN)) * 4;
#pragma unroll
        for (int t = 0; t < 4; t++) r[t + 1] = rr[t];
    }
    float* Wb = W + (size_t)b * NM * NM;
#pragma unroll
    for (int i = 0; i < 5; i++)
#pragma unroll
        for (int j = 0; j < 5; j++) atomicAdd(&Wb[(size_t)r[i] * NM + r[j]], cval);
}

// ---- d_is[row] = 1/sqrt(rowsum(W) + 1 (identity) + eps); one wave per row ----
__global__ __launch_bounds__(256) void k_dis(const float* __restrict__ W, float* __restrict__ dis) {
    int wid = (blockIdx.x * 256 + threadIdx.x) >> 6;  // global row = b*NM + i
    int lane = threadIdx.x & 63;
    if (wid >= NB * NM) return;
    const float* row = W + (size_t)wid * NM;
    float s = 0.f;
    for (int t = lane; t < NM; t += 64) s += row[t];
    s = wave_reduce_add(s);
    if (lane == 0) dis[wid] = 1.0f / sqrtf(s + 1.0f + 1e-8f);
}

// ---- W (f32) -> W16 (bf16), RNE ----
__global__ __launch_bounds__(256) void k_w16(const float* __restrict__ W,
                                             unsigned short* __restrict__ W16) {
    size_t i = ((size_t)blockIdx.x * 256 + threadIdx.x) * 4;
    f32x4 v = *(const f32x4*)(W + i);
    u16x4 o;
    o[0] = f2bf(v[0]); o[1] = f2bf(v[1]); o[2] = f2bf(v[2]); o[3] = f2bf(v[3]);
    *(u16x4*)(W16 + i) = o;
}

// ---- Z0[b,c,m] = dis[b,m] * joint(b,c,m) (bf16); Xh[b,c,m] = 0.9 * joint ----
__global__ void k_y0(const float* __restrict__ feat, const float* __restrict__ tfT,
                     const float* __restrict__ dis, unsigned short* __restrict__ Z0,
                     float* __restrict__ Xh) {
    int bc = blockIdx.x;            // b*NC + c
    int b = bc >> 7, c = bc & 127;
    for (int m = threadIdx.x; m < NM; m += 256) {
        float v = (m < NN) ? feat[(size_t)bc * NN + m] : tfT[(size_t)c * NA + (m - NN)];
        Z0[(size_t)bc * NM + m] = f2bf(dis[b * NM + m] * v);
        Xh[(size_t)bc * NM + m] = 0.9f * v;
    }
}

// ---- MFMA propagation on Z = D^-1/2 Y:
//      s = W @ Zin ; o(=Y_next) = dis*(s + Zin) ; Xh += coef*o ; Zout = dis*o
//      A-frag: W16 row-major (m,k); B-frag: Zin (c,m) == B^T layout; no LDS.
__global__ __launch_bounds__(256) void k_prop(const unsigned short* __restrict__ W16,
                                              const float* __restrict__ dis,
                                              const unsigned short* __restrict__ Zin,
                                              unsigned short* __restrict__ Zout,
                                              float* __restrict__ Xh, float coef) {
    int b = blockIdx.z;
    int m0 = blockIdx.x * 64;   // 12 tiles
    int c0 = blockIdx.y * 64;   // 2 tiles
    int tid = threadIdx.x;
    int w = tid >> 6, l = tid & 63;
    int lr = l & 15, lg = l >> 4;

    const unsigned short* Ap = W16 + ((size_t)b * NM + m0 + w * 16 + lr) * NM + lg * 8;
    const unsigned short* Bp = Zin + ((size_t)b * NC + c0 + lr) * NM + lg * 8;

    f32x4 acc[4];
#pragma unroll
    for (int f = 0; f < 4; f++) { acc[f][0] = 0.f; acc[f][1] = 0.f; acc[f][2] = 0.f; acc[f][3] = 0.f; }

    bf16x8 a0 = *(const bf16x8*)(Ap);
    bf16x8 b0[4];
#pragma unroll
    for (int f = 0; f < 4; f++) b0[f] = *(const bf16x8*)(Bp + (size_t)(f * 16) * NM);

    for (int k0 = 0; k0 < NM - 32; k0 += 32) {
        bf16x8 a1 = *(const bf16x8*)(Ap + k0 + 32);
        bf16x8 b1[4];
#pragma unroll
        for (int f = 0; f < 4; f++) b1[f] = *(const bf16x8*)(Bp + (size_t)(f * 16) * NM + k0 + 32);
#pragma unroll
        for (int f = 0; f < 4; f++)
            acc[f] = __builtin_amdgcn_mfma_f32_16x16x32_bf16(a0, b0[f], acc[f], 0, 0, 0);
        a0 = a1;
#pragma unroll
        for (int f = 0; f < 4; f++) b0[f] = b1[f];
    }
#pragma unroll
    for (int f = 0; f < 4; f++)
        acc[f] = __builtin_amdgcn_mfma_f32_16x16x32_bf16(a0, b0[f], acc[f], 0, 0, 0);

    // epilogue: lane holds D[row=lg*4+r][col=lr] per frag f
    int mb = m0 + w * 16 + lg * 4;
    f32x4 dv = *(const f32x4*)(dis + b * NM + mb);
#pragma unroll
    for (int f = 0; f < 4; f++) {
        int c = c0 + f * 16 + lr;
        size_t off = ((size_t)b * NC + c) * NM + mb;
        u16x4 zi = *(const u16x4*)(Zin + off);
        f32x4 xh = *(const f32x4*)(Xh + off);
        u16x4 zo;
#pragma unroll
        for (int r = 0; r < 4; r++) {
            float o = dv[r] * (acc[f][r] + bf2f(zi[r]));
            xh[r] += coef * o;
            zo[r] = f2bf(dv[r] * o);
        }
        *(f32x4*)(Xh + off) = xh;
        *(u16x4*)(Zout + off) = zo;
    }
}

// ---- X_hat (B,C,N) = Xh[:, :, :N] (contiguous row copy) ----
__global__ void k_xhat_out(const float* __restrict__ Xh, float* __restrict__ out) {
    int bc = blockIdx.x;  // b*NC + c
    int n = threadIdx.x;
    out[(size_t)bc * NN + n] = Xh[(size_t)bc * NM + n];
}

// ---- X_E[b,k,c] = inv_edge[b,k] * sum_n (adj[b,n,k]*isn[b,n]) * Xh[b,c,n] ----
__global__ __launch_bounds__(256) void k_xe(const float* __restrict__ adj,
                                            const float* __restrict__ isn,
                                            const float* __restrict__ inv_edge,
                                            const float* __restrict__ Xh,
                                            float* __restrict__ outE) {
    __shared__ float ta[16][17];  // [n_local][k_local]
    __shared__ float tz[16][17];  // [c_local][n_local]
    int b = blockIdx.z;
    int k0 = blockIdx.y * 16;  // 6 tiles
    int c0 = blockIdx.x * 16;  // 8 tiles
    int tx = threadIdx.x & 15;
    int ty = threadIdx.x >> 4;
    float acc = 0.f;
    for (int n0 = 0; n0 < NN; n0 += 16) {
        int n = n0 + ty;
        ta[ty][tx] = adj[(size_t)(b * NN + n) * NK + k0 + tx] * isn[b * NN + n];
        tz[ty][tx] = Xh[((size_t)b * NC + c0 + ty) * NM + n0 + tx];
        __syncthreads();
#pragma unroll
        for (int nn = 0; nn < 16; nn++) acc += ta[nn][ty] * tz[tx][nn];
        __syncthreads();
    }
    int k = k0 + ty, c = c0 + tx;
    outE[(size_t)(b * NK + k) * NC + c] = inv_edge[b * NK + k] * acc;
}

extern "C" void kernel_launch(void* const* d_in, const int* in_sizes, int n_in,
                              void* d_out, int out_size, void* d_ws, size_t ws_size,
                              hipStream_t stream) {
    (void)in_sizes; (void)n_in; (void)out_size; (void)ws_size;
    const float* features = (const float*)d_in[0];  // (B,C,N)
    const float* adj      = (const float*)d_in[1];  // (B,N,K)
    const float* tf       = (const float*)d_in[2];  // (A,C)
    const float* mem_adj  = (const float*)d_in[3];  // (A,K)
    float* out_xhat = (float*)d_out;                 // (B,C,N)
    float* out_xe   = out_xhat + (size_t)NB * NC * NN;  // (B,K,C)

    float* p = (float*)d_ws;
    float* memN_T  = p; p += (size_t)NC * NA;
    float* tfT     = p; p += (size_t)NC * NA;
    float* Xn      = p; p += (size_t)NB * NN * NC;
    float* sim     = p; p += (size_t)NB * NN * NA;
    float* sc_adj  = p; p += NB * NK;
    float* inv_edge= p; p += NB * NK;
    float* dmem_inv= p; p += NK;
    float* isn     = p; p += NB * NN;
    float* dis     = p; p += NB * NM;
    float* W       = p; p += (size_t)NB * NM * NM;
    float* Xh      = p; p += (size_t)NB * NC * NM;   // (B,C,M) f32
    unsigned short* W16 = (unsigned short*)p;        // (B,M,M) bf16
    unsigned short* Z0  = W16 + (size_t)NB * NM * NM;
    unsigned short* Z1  = Z0 + (size_t)NB * NC * NM;
    int* knn = (int*)(Z1 + (size_t)NB * NC * NM);
    int* rev = knn + NB * NN * 4;

    hipMemsetAsync(W, 0, sizeof(float) * (size_t)NB * NM * NM, stream);
    k_norm_mem<<<NA, NC, 0, stream>>>(tf, memN_T, tfT);
    k_norm_x<<<NB * NN, NC, 0, stream>>>(features, Xn);
    k_dmem<<<(NK * 64 + 255) / 256, 256, 0, stream>>>(mem_adj, dmem_inv);
    k_edge_deg<<<NB * NK / 4, 256, 0, stream>>>(adj, sc_adj, inv_edge);
    k_node_deg<<<NB * NN / 4, 256, 0, stream>>>(adj, isn);
    k_sim<<<NB * NN / 8, 512, 0, stream>>>(Xn, memN_T, sim);
    k_knn<<<NB * NN / 4, 256, 0, stream>>>(sim, knn);
    k_rev<<<NB * NA / 4, 256, 0, stream>>>(sim, rev);
    k_memW<<<dim3(NA / 16, NA / 16), dim3(16, 16), 0, stream>>>(mem_adj, dmem_inv, W);
    k_adjW<<<dim3(NN / 16, NN / 16, NB), dim3(16, 16), 0, stream>>>(adj, sc_adj, W);
    k_scatter<<<NB * NM / 256, 256, 0, stream>>>(knn, rev, W);
    k_dis<<<NB * NM / 4, 256, 0, stream>>>(W, dis);
    k_w16<<<(int)(((size_t)NB * NM * NM / 4 + 255) / 256), 256, 0, stream>>>(W, W16);
    k_y0<<<NB * NC, 256, 0, stream>>>(features, tfT, dis, Z0, Xh);
    dim3 pg(NM / 64, NC / 64, NB);
    k_prop<<<pg, 256, 0, stream>>>(W16, dis, Z0, Z1, Xh, 0.09f);
    k_prop<<<pg, 256, 0, stream>>>(W16, dis, Z1, Z0, Xh, 0.009f);
    k_prop<<<pg, 256, 0, stream>>>(W16, dis, Z0, Z1, Xh, 0.001f);
    k_xhat_out<<<NB * NC, NN, 0, stream>>>(Xh, out_xhat);
    k_xe<<<dim3(NC / 16, NK / 16, NB), 256, 0, stream>>>(adj, isn, inv_edge, Xh, out_xe);
}

// Round 6
// 145.849 us; speedup vs baseline: 5.5845x; 1.1231x over previous
//
#include <hip/hip_runtime.h>

#define NB 8
#define NC 128
#define NN 256
#define NK 96
#define NA 512
#define NM 768   // NN + NA

typedef __attribute__((ext_vector_type(8))) short bf16x8;
typedef __attribute__((ext_vector_type(4))) float f32x4;
typedef __attribute__((ext_vector_type(4))) unsigned short u16x4;

__device__ __forceinline__ float wave_reduce_add(float s) {
    for (int o = 32; o > 0; o >>= 1) s += __shfl_down(s, o, 64);
    return s;
}

// f32 -> bf16 round-to-nearest-even
__device__ __forceinline__ unsigned short f2bf(float x) {
    unsigned u = __float_as_uint(x);
    unsigned r = (u + 0x7FFFu + ((u >> 16) & 1u)) >> 16;
    return (unsigned short)r;
}
__device__ __forceinline__ float bf2f(unsigned short h) {
    return __uint_as_float((unsigned)h << 16);
}

// ---- fused normalize: blocks [0,NA) memory rows -> memN_T,tfT ; [NA, NA+B*N) test rows -> Xn
__global__ void k_norm(const float* __restrict__ tf, const float* __restrict__ feat,
                       float* __restrict__ memN_T, float* __restrict__ tfT,
                       float* __restrict__ Xn) {
    __shared__ float p[2];
    int bi = blockIdx.x, c = threadIdx.x;
    if (bi < NA) {
        int a = bi;
        float v = tf[a * NC + c];
        float s = wave_reduce_add(v * v);
        if ((c & 63) == 0) p[c >> 6] = s;
        __syncthreads();
        float norm = sqrtf(p[0] + p[1]);
        memN_T[c * NA + a] = v / fmaxf(norm, 1e-12f);
        tfT[c * NA + a] = v;
    } else {
        int g = bi - NA;                 // b*NN + n
        int b = g >> 8, n = g & 255;
        float v = feat[(b * NC + c) * NN + n];
        float s = wave_reduce_add(v * v);
        if ((c & 63) == 0) p[c >> 6] = s;
        __syncthreads();
        float norm = sqrtf(p[0] + p[1]);
        Xn[g * NC + c] = v / fmaxf(norm, 1e-12f);
    }
}

// ---- fused degrees: waves [0,NK) dmem ; [NK, NK+B*K) edge ; rest node ----
__global__ __launch_bounds__(256) void k_deg(const float* __restrict__ mem_adj,
                                             const float* __restrict__ adj,
                                             float* __restrict__ dmem_inv,
                                             float* __restrict__ sc_adj,
                                             float* __restrict__ inv_edge,
                                             float* __restrict__ isn) {
    int wid = (blockIdx.x * 256 + threadIdx.x) >> 6;
    int lane = threadIdx.x & 63;
    if (wid < NK) {
        float s = 0.f;
        for (int a = lane; a < NA; a += 64) s += mem_adj[(size_t)a * NK + wid];
        s = wave_reduce_add(s);
        if (lane == 0) dmem_inv[wid] = 1.0f / (s + 1e-8f);
    } else if (wid < NK + NB * NK) {
        int w2 = wid - NK;
        int b = w2 / NK, k = w2 % NK;
        float s = 0.f;
        for (int n = lane; n < NN; n += 64) s += adj[(size_t)(b * NN + n) * NK + k];
        s = wave_reduce_add(s);
        if (lane == 0) {
            sc_adj[w2] = 1.0f / (s + 1e-8f);
            inv_edge[w2] = 1.0f / fmaxf(s, 1e-8f);
        }
    } else if (wid < NK + NB * NK + NB * NN) {
        int w3 = wid - NK - NB * NK;     // b*NN + n
        const float* row = adj + (size_t)w3 * NK;
        float s = (lane < NK) ? row[lane] : 0.f;
        if (lane + 64 < NK) s += row[lane + 64];   // NK=96: lanes 0..31 pick up cols 64..95
        s = wave_reduce_add(s);
        if (lane == 0) isn[w3] = 1.0f / sqrtf(fmaxf(s, 1e-8f));
    }
}

// ---- cosine similarity sim[b*N+n][a] = <Xn_row, memN_col> ----
__global__ __launch_bounds__(512) void k_sim(const float* __restrict__ Xn,
                                             const float* __restrict__ memN_T,
                                             float* __restrict__ sim) {
    __shared__ float xr[8][NC];
    int g0 = blockIdx.x * 8;
    int t = threadIdx.x;
    for (int i = t; i < 8 * NC; i += 512) xr[i / NC][i % NC] = Xn[g0 * NC + i];
    __syncthreads();
    float acc[8] = {0, 0, 0, 0, 0, 0, 0, 0};
    int a = t;  // 0..511
    for (int c = 0; c < NC; c++) {
        float m = memN_T[c * NA + a];
#pragma unroll
        for (int r = 0; r < 8; r++) acc[r] += xr[r][c] * m;
    }
#pragma unroll
    for (int r = 0; r < 8; r++) sim[(size_t)(g0 + r) * NA + a] = acc[r];
}

// ---- sortable key: higher value wins, tie -> lower index (== lax.top_k order) ----
__device__ __forceinline__ unsigned long long pack_key(float v, unsigned idx) {
    unsigned u = __float_as_uint(v);
    u = (u & 0x80000000u) ? ~u : (u | 0x80000000u);
    return ((unsigned long long)u << 32) | (unsigned long long)(0xFFFFFFFFu - idx);
}

__device__ __forceinline__ void ins4(unsigned long long v, unsigned long long* k) {
    if (v > k[3]) {
        if (v > k[1]) {
            if (v > k[0]) { k[3] = k[2]; k[2] = k[1]; k[1] = k[0]; k[0] = v; }
            else         { k[3] = k[2]; k[2] = k[1]; k[1] = v; }
        } else {
            if (v > k[2]) { k[3] = k[2]; k[2] = v; }
            else          { k[3] = v; }
        }
    }
}

// butterfly merge of per-lane sorted-desc top-4 lists -> global top-4 in every lane
__device__ __forceinline__ void merge_top4(unsigned long long* k) {
#pragma unroll
    for (int d = 1; d < 64; d <<= 1) {
        unsigned long long p0 = __shfl_xor(k[0], d, 64);
        unsigned long long p1 = __shfl_xor(k[1], d, 64);
        unsigned long long p2 = __shfl_xor(k[2], d, 64);
        unsigned long long p3 = __shfl_xor(k[3], d, 64);
        unsigned long long c0 = k[0] > p3 ? k[0] : p3;
        unsigned long long c1 = k[1] > p2 ? k[1] : p2;
        unsigned long long c2 = k[2] > p1 ? k[2] : p1;
        unsigned long long c3 = k[3] > p0 ? k[3] : p0;
        unsigned long long d0 = c0 > c2 ? c0 : c2, d2 = c0 > c2 ? c2 : c0;
        unsigned long long d1 = c1 > c3 ? c1 : c3, d3 = c1 > c3 ? c3 : c1;
        k[0] = d0 > d1 ? d0 : d1; k[1] = d0 > d1 ? d1 : d0;
        k[2] = d2 > d3 ? d2 : d3; k[3] = d2 > d3 ? d3 : d2;
    }
}

// ---- fused top-4: waves [0, B*N) knn rows ; [B*N, B*N+B*A) rev cols ----
__global__ __launch_bounds__(256) void k_knnrev(const float* __restrict__ sim,
                                                int* __restrict__ knn,
                                                int* __restrict__ rev) {
    int wid = (blockIdx.x * 256 + threadIdx.x) >> 6;
    int lane = threadIdx.x & 63;
    unsigned long long k[4] = {0, 0, 0, 0};
    if (wid < NB * NN) {
        const float* row = sim + (size_t)wid * NA;
#pragma unroll
        for (int t = 0; t < NA / 64; t++) {
            int a = lane + 64 * t;
            ins4(pack_key(row[a], (unsigned)a), k);
        }
        merge_top4(k);
        if (lane < 4) knn[wid * 4 + lane] = (int)(0xFFFFFFFFu - (unsigned)k[lane]);
    } else {
        int w2 = wid - NB * NN;          // b*NA + a
        int b = w2 >> 9, a = w2 & 511;
        const float* base = sim + (size_t)b * NN * NA + a;
#pragma unroll
        for (int t = 0; t < NN / 64; t++) {
            int n = lane + 64 * t;
            ins4(pack_key(base[(size_t)n * NA], (unsigned)n), k);
        }
        merge_top4(k);
        if (lane < 4) rev[w2 * 4 + lane] = (int)(0xFFFFFFFFu - (unsigned)k[lane]);
    }
}

// ---- fused W block builder:
//   blocks [0,1024)      : A x A mem block (batch-independent, broadcast to all b)
//   blocks [1024,3072)   : N x N adj block per batch
//   blocks [3072,5120)   : zero the off-diagonal N x A / A x N regions
__global__ __launch_bounds__(256) void k_wblocks(const float* __restrict__ mem_adj,
                                                 const float* __restrict__ dmem_inv,
                                                 const float* __restrict__ adj,
                                                 const float* __restrict__ sc_adj,
                                                 float* __restrict__ W) {
    __shared__ float ta[16][NK + 1];
    __shared__ float tb[16][NK + 1];
    int bi = blockIdx.x, tid = threadIdx.x;
    int tx = tid & 15, ty = tid >> 4;
    if (bi < 1024) {
        int a0 = (bi >> 5) * 16, a1 = (bi & 31) * 16;
        for (int i = tid; i < 16 * NK; i += 256) {
            int r = i / NK, j = i % NK;
            ta[r][j] = mem_adj[(a0 + r) * NK + j] * dmem_inv[j];
            tb[r][j] = mem_adj[(a1 + r) * NK + j];
        }
        __syncthreads();
        float s = 0.f;
        for (int j = 0; j < NK; j++) s += ta[ty][j] * tb[tx][j];
        int row = NN + a0 + ty, col = NN + a1 + tx;
        for (int b = 0; b < NB; b++) W[(size_t)b * NM * NM + (size_t)row * NM + col] = s;
    } else if (bi < 3072) {
        int t = bi - 1024;
        int n1 = (t & 15) * 16, n0 = ((t >> 4) & 15) * 16, b = t >> 8;
        const float* adjb = adj + (size_t)b * NN * NK;
        const float* scb = sc_adj + b * NK;
        for (int i = tid; i < 16 * NK; i += 256) {
            int r = i / NK, j = i % NK;
            ta[r][j] = adjb[(n0 + r) * NK + j] * scb[j];
            tb[r][j] = adjb[(n1 + r) * NK + j];
        }
        __syncthreads();
        float s = 0.f;
        for (int j = 0; j < NK; j++) s += ta[ty][j] * tb[tx][j];
        W[(size_t)b * NM * NM + (size_t)(n0 + ty) * NM + (n1 + tx)] = s;
    } else {
        int t = bi - 3072;               // [0, 2048)
        int b = t >> 8;
        int v = (t & 255) * 256 + tid;   // [0, 65536) float4 slots per batch
        int row, col4;
        if (v < 32768) { row = v >> 7; col4 = 64 + (v & 127); }      // rows 0..255, cols 256..767
        else { int v2 = v - 32768; row = 256 + (v2 >> 6); col4 = v2 & 63; }  // rows 256..767, cols 0..255
        f32x4 z; z[0] = 0.f; z[1] = 0.f; z[2] = 0.f; z[3] = 0.f;
        *(f32x4*)(W + (size_t)b * NM * NM + (size_t)row * NM + col4 * 4) = z;
    }
}

// ---- cross columns: each has exactly 5 ones (deg 5), 25-entry outer-product scatter ----
__global__ void k_scatter(const int* __restrict__ knn, const int* __restrict__ rev,
                          float* __restrict__ W) {
    int g = blockIdx.x * blockDim.x + threadIdx.x;  // b*NM + col
    if (g >= NB * NM) return;
    int b = g / NM, col = g % NM;
    const float cval = 1.0f / (5.0f + 1e-8f);
    int r[5];
    r[0] = col;
    if (col < NN) {
        const int* kk = knn + (size_t)(b * NN + col) * 4;
#pragma unroll
        for (int t = 0; t < 4; t++) r[t + 1] = NN + kk[t];
    } else {
        const int* rr = rev + (size_t)(b * NA + (col - NN)) * 4;
#pragma unroll
        for (int t = 0; t < 4; t++) r[t + 1] = rr[t];
    }
    float* Wb = W + (size_t)b * NM * NM;
#pragma unroll
    for (int i = 0; i < 5; i++)
#pragma unroll
        for (int j = 0; j < 5; j++) atomicAdd(&Wb[(size_t)r[i] * NM + r[j]], cval);
}

// ---- fused: W(f32) -> W16(bf16) + dis = 1/sqrt(rowsum+1+eps); one wave per row ----
__global__ __launch_bounds__(256) void k_w16dis(const float* __restrict__ W,
                                                unsigned short* __restrict__ W16,
                                                float* __restrict__ dis) {
    int wid = (blockIdx.x * 256 + threadIdx.x) >> 6;  // b*NM + row
    int lane = threadIdx.x & 63;
    if (wid >= NB * NM) return;
    const float* row = W + (size_t)wid * NM;
    unsigned short* row16 = W16 + (size_t)wid * NM;
    float s = 0.f;
#pragma unroll
    for (int t = 0; t < 3; t++) {
        int e = (lane + t * 64) * 4;
        f32x4 v = *(const f32x4*)(row + e);
        s += (v[0] + v[1]) + (v[2] + v[3]);
        u16x4 o;
        o[0] = f2bf(v[0]); o[1] = f2bf(v[1]); o[2] = f2bf(v[2]); o[3] = f2bf(v[3]);
        *(u16x4*)(row16 + e) = o;
    }
    s = wave_reduce_add(s);
    if (lane == 0) dis[wid] = 1.0f / sqrtf(s + 1.0f + 1e-8f);
}

// ---- Z0[b,c,m] = dis[b,m] * joint(b,c,m) (bf16); Xh[b,c,m] = 0.9 * joint ----
__global__ void k_y0(const float* __restrict__ feat, const float* __restrict__ tfT,
                     const float* __restrict__ dis, unsigned short* __restrict__ Z0,
                     float* __restrict__ Xh) {
    int bc = blockIdx.x;            // b*NC + c
    int b = bc >> 7, c = bc & 127;
    for (int m = threadIdx.x; m < NM; m += 256) {
        float v = (m < NN) ? feat[(size_t)bc * NN + m] : tfT[(size_t)c * NA + (m - NN)];
        Z0[(size_t)bc * NM + m] = f2bf(dis[b * NM + m] * v);
        Xh[(size_t)bc * NM + m] = 0.9f * v;
    }
}

// ---- MFMA propagation on Z = D^-1/2 Y:
//      s = W @ Zin ; o(=Y_next) = dis*(s + Zin) ; Xh += coef*o ; Zout = dis*o
//      A-frag: W16 row-major (m,k); B-frag: Zin (c,m) == B^T layout; no LDS.
//      block: m-tile 32 (2 wave-rows) x c-tile 64 (2 wave-cols x 2 frags)
__global__ __launch_bounds__(256) void k_prop(const unsigned short* __restrict__ W16,
                                              const float* __restrict__ dis,
                                              const unsigned short* __restrict__ Zin,
                                              unsigned short* __restrict__ Zout,
                                              float* __restrict__ Xh, float coef) {
    int b = blockIdx.z;
    int m0 = blockIdx.x * 32;   // 24 tiles
    int c0 = blockIdx.y * 64;   // 2 tiles
    int tid = threadIdx.x;
    int w = tid >> 6, l = tid & 63;
    int wm = w >> 1, wc = w & 1;
    int lr = l & 15, lg = l >> 4;

    const unsigned short* Ap = W16 + ((size_t)b * NM + m0 + wm * 16 + lr) * NM + lg * 8;
    const unsigned short* Bp = Zin + ((size_t)b * NC + c0 + wc * 32 + lr) * NM + lg * 8;

    f32x4 acc[2];
#pragma unroll
    for (int f = 0; f < 2; f++) { acc[f][0] = 0.f; acc[f][1] = 0.f; acc[f][2] = 0.f; acc[f][3] = 0.f; }

    bf16x8 a0 = *(const bf16x8*)(Ap);
    bf16x8 b0[2];
#pragma unroll
    for (int f = 0; f < 2; f++) b0[f] = *(const bf16x8*)(Bp + (size_t)(f * 16) * NM);

    for (int k0 = 0; k0 < NM - 32; k0 += 32) {
        bf16x8 a1 = *(const bf16x8*)(Ap + k0 + 32);
        bf16x8 b1[2];
#pragma unroll
        for (int f = 0; f < 2; f++) b1[f] = *(const bf16x8*)(Bp + (size_t)(f * 16) * NM + k0 + 32);
#pragma unroll
        for (int f = 0; f < 2; f++)
            acc[f] = __builtin_amdgcn_mfma_f32_16x16x32_bf16(a0, b0[f], acc[f], 0, 0, 0);
        a0 = a1;
#pragma unroll
        for (int f = 0; f < 2; f++) b0[f] = b1[f];
    }
#pragma unroll
    for (int f = 0; f < 2; f++)
        acc[f] = __builtin_amdgcn_mfma_f32_16x16x32_bf16(a0, b0[f], acc[f], 0, 0, 0);

    // epilogue: lane holds D[row=lg*4+r][col=lr] per frag f
    int mb = m0 + wm * 16 + lg * 4;
    f32x4 dv = *(const f32x4*)(dis + b * NM + mb);
#pragma unroll
    for (int f = 0; f < 2; f++) {
        int c = c0 + wc * 32 + f * 16 + lr;
        size_t off = ((size_t)b * NC + c) * NM + mb;
        u16x4 zi = *(const u16x4*)(Zin + off);
        f32x4 xh = *(const f32x4*)(Xh + off);
        u16x4 zo;
#pragma unroll
        for (int r = 0; r < 4; r++) {
            float o = dv[r] * (acc[f][r] + bf2f(zi[r]));
            xh[r] += coef * o;
            zo[r] = f2bf(dv[r] * o);
        }
        *(f32x4*)(Xh + off) = xh;
        *(u16x4*)(Zout + off) = zo;
    }
}

// ---- X_hat (B,C,N) = Xh[:, :, :N] (contiguous row copy) ----
__global__ void k_xhat_out(const float* __restrict__ Xh, float* __restrict__ out) {
    int bc = blockIdx.x;  // b*NC + c
    int n = threadIdx.x;
    out[(size_t)bc * NN + n] = Xh[(size_t)bc * NM + n];
}

// ---- X_E[b,k,c] = inv_edge[b,k] * sum_n (adj[b,n,k]*isn[b,n]) * Xh[b,c,n] ----
__global__ __launch_bounds__(256) void k_xe(const float* __restrict__ adj,
                                            const float* __restrict__ isn,
                                            const float* __restrict__ inv_edge,
                                            const float* __restrict__ Xh,
                                            float* __restrict__ outE) {
    __shared__ float ta[16][17];  // [n_local][k_local]
    __shared__ float tz[16][17];  // [c_local][n_local]
    int b = blockIdx.z;
    int k0 = blockIdx.y * 16;  // 6 tiles
    int c0 = blockIdx.x * 16;  // 8 tiles
    int tx = threadIdx.x & 15;
    int ty = threadIdx.x >> 4;
    float acc = 0.f;
    for (int n0 = 0; n0 < NN; n0 += 16) {
        int n = n0 + ty;
        ta[ty][tx] = adj[(size_t)(b * NN + n) * NK + k0 + tx] * isn[b * NN + n];
        tz[ty][tx] = Xh[((size_t)b * NC + c0 + ty) * NM + n0 + tx];
        __syncthreads();
#pragma unroll
        for (int nn = 0; nn < 16; nn++) acc += ta[nn][ty] * tz[tx][nn];
        __syncthreads();
    }
    int k = k0 + ty, c = c0 + tx;
    outE[(size_t)(b * NK + k) * NC + c] = inv_edge[b * NK + k] * acc;
}

extern "C" void kernel_launch(void* const* d_in, const int* in_sizes, int n_in,
                              void* d_out, int out_size, void* d_ws, size_t ws_size,
                              hipStream_t stream) {
    (void)in_sizes; (void)n_in; (void)out_size; (void)ws_size;
    const float* features = (const float*)d_in[0];  // (B,C,N)
    const float* adj      = (const float*)d_in[1];  // (B,N,K)
    const float* tf       = (const float*)d_in[2];  // (A,C)
    const float* mem_adj  = (const float*)d_in[3];  // (A,K)
    float* out_xhat = (float*)d_out;                 // (B,C,N)
    float* out_xe   = out_xhat + (size_t)NB * NC * NN;  // (B,K,C)

    float* p = (float*)d_ws;
    float* memN_T  = p; p += (size_t)NC * NA;
    float* tfT     = p; p += (size_t)NC * NA;
    float* Xn      = p; p += (size_t)NB * NN * NC;
    float* sim     = p; p += (size_t)NB * NN * NA;
    float* sc_adj  = p; p += NB * NK;
    float* inv_edge= p; p += NB * NK;
    float* dmem_inv= p; p += NK;
    float* isn     = p; p += NB * NN;
    float* dis     = p; p += NB * NM;
    float* W       = p; p += (size_t)NB * NM * NM;
    float* Xh      = p; p += (size_t)NB * NC * NM;   // (B,C,M) f32
    unsigned short* W16 = (unsigned short*)p;        // (B,M,M) bf16
    unsigned short* Z0  = W16 + (size_t)NB * NM * NM;
    unsigned short* Z1  = Z0 + (size_t)NB * NC * NM;
    int* knn = (int*)(Z1 + (size_t)NB * NC * NM);
    int* rev = knn + NB * NN * 4;

    k_norm<<<NA + NB * NN, NC, 0, stream>>>(tf, features, memN_T, tfT, Xn);
    k_deg<<<(NK + NB * NK + NB * NN + 3) / 4, 256, 0, stream>>>(mem_adj, adj, dmem_inv,
                                                                sc_adj, inv_edge, isn);
    k_sim<<<NB * NN / 8, 512, 0, stream>>>(Xn, memN_T, sim);
    k_knnrev<<<(NB * NN + NB * NA) / 4, 256, 0, stream>>>(sim, knn, rev);
    k_wblocks<<<5120, 256, 0, stream>>>(mem_adj, dmem_inv, adj, sc_adj, W);
    k_scatter<<<NB * NM / 256, 256, 0, stream>>>(knn, rev, W);
    k_w16dis<<<NB * NM / 4, 256, 0, stream>>>(W, W16, dis);
    k_y0<<<NB * NC, 256, 0, stream>>>(features, tfT, dis, Z0, Xh);
    dim3 pg(NM / 32, NC / 64, NB);
    k_prop<<<pg, 256, 0, stream>>>(W16, dis, Z0, Z1, Xh, 0.09f);
    k_prop<<<pg, 256, 0, stream>>>(W16, dis, Z1, Z0, Xh, 0.009f);
    k_prop<<<pg, 256, 0, stream>>>(W16, dis, Z0, Z1, Xh, 0.001f);
    k_xhat_out<<<NB * NC, NN, 0, stream>>>(Xh, out_xhat);
    k_xe<<<dim3(NC / 16, NK / 16, NB), 256, 0, stream>>>(adj, isn, inv_edge, Xh, out_xe);
}

// Round 7
// 136.991 us; speedup vs baseline: 5.9456x; 1.0647x over previous
//
#include <hip/hip_runtime.h>

#define NB 8
#define NC 128
#define NN 256
#define NK 96
#define NA 512
#define NM 768   // NN + NA

typedef __attribute__((ext_vector_type(8))) short bf16x8;
typedef __attribute__((ext_vector_type(4))) float f32x4;
typedef __attribute__((ext_vector_type(4))) unsigned short u16x4;

__device__ __forceinline__ float wave_reduce_add(float s) {
    for (int o = 32; o > 0; o >>= 1) s += __shfl_down(s, o, 64);
    return s;
}

// f32 -> bf16 round-to-nearest-even
__device__ __forceinline__ unsigned short f2bf(float x) {
    unsigned u = __float_as_uint(x);
    unsigned r = (u + 0x7FFFu + ((u >> 16) & 1u)) >> 16;
    return (unsigned short)r;
}
__device__ __forceinline__ float bf2f(unsigned short h) {
    return __uint_as_float((unsigned)h << 16);
}

// ---- fused normalize + degrees (128 threads/block)
//   blocks [0, NA)            : memory feature rows -> memN_T, tfT
//   blocks [NA, NA+B*N)       : test feature rows -> Xn
//   blocks beyond (2 waves ea): degree reductions (dmem / edge / node)
#define NORM_BLKS (NA + NB * NN)
#define DEG_WAVES (NK + NB * NK + NB * NN)
__global__ __launch_bounds__(128) void k_normdeg(const float* __restrict__ tf,
                                                 const float* __restrict__ feat,
                                                 const float* __restrict__ mem_adj,
                                                 const float* __restrict__ adj,
                                                 float* __restrict__ memN_T,
                                                 float* __restrict__ tfT,
                                                 float* __restrict__ Xn,
                                                 float* __restrict__ dmem_inv,
                                                 float* __restrict__ sc_adj,
                                                 float* __restrict__ inv_edge,
                                                 float* __restrict__ isn) {
    __shared__ float p[2];
    int bi = blockIdx.x, c = threadIdx.x;
    if (bi < NA) {
        int a = bi;
        float v = tf[a * NC + c];
        float s = wave_reduce_add(v * v);
        if ((c & 63) == 0) p[c >> 6] = s;
        __syncthreads();
        float norm = sqrtf(p[0] + p[1]);
        memN_T[c * NA + a] = v / fmaxf(norm, 1e-12f);
        tfT[c * NA + a] = v;
    } else if (bi < NORM_BLKS) {
        int g = bi - NA;                 // b*NN + n
        int b = g >> 8, n = g & 255;
        float v = feat[(b * NC + c) * NN + n];
        float s = wave_reduce_add(v * v);
        if ((c & 63) == 0) p[c >> 6] = s;
        __syncthreads();
        float norm = sqrtf(p[0] + p[1]);
        Xn[g * NC + c] = v / fmaxf(norm, 1e-12f);
    } else {
        int wid = (bi - NORM_BLKS) * 2 + (c >> 6);
        int lane = c & 63;
        if (wid < NK) {
            float s = 0.f;
            for (int a = lane; a < NA; a += 64) s += mem_adj[(size_t)a * NK + wid];
            s = wave_reduce_add(s);
            if (lane == 0) dmem_inv[wid] = 1.0f / (s + 1e-8f);
        } else if (wid < NK + NB * NK) {
            int w2 = wid - NK;
            int b = w2 / NK, k = w2 % NK;
            float s = 0.f;
            for (int n = lane; n < NN; n += 64) s += adj[(size_t)(b * NN + n) * NK + k];
            s = wave_reduce_add(s);
            if (lane == 0) {
                sc_adj[w2] = 1.0f / (s + 1e-8f);
                inv_edge[w2] = 1.0f / fmaxf(s, 1e-8f);
            }
        } else if (wid < DEG_WAVES) {
            int w3 = wid - NK - NB * NK;     // b*NN + n
            const float* row = adj + (size_t)w3 * NK;
            float s = (lane < NK) ? row[lane] : 0.f;
            if (lane + 64 < NK) s += row[lane + 64];   // NK=96
            s = wave_reduce_add(s);
            if (lane == 0) isn[w3] = 1.0f / sqrtf(fmaxf(s, 1e-8f));
        }
    }
}

// ---- cosine similarity; writes n-major sim AND a-major simT ----
__global__ __launch_bounds__(512) void k_sim(const float* __restrict__ Xn,
                                             const float* __restrict__ memN_T,
                                             float* __restrict__ sim,
                                             float* __restrict__ simT) {
    __shared__ float xr[8][NC];
    int g0 = blockIdx.x * 8;
    int b = g0 >> 8, n0 = g0 & 255;
    int t = threadIdx.x;
    for (int i = t; i < 8 * NC; i += 512) xr[i / NC][i % NC] = Xn[g0 * NC + i];
    __syncthreads();
    float acc[8] = {0, 0, 0, 0, 0, 0, 0, 0};
    int a = t;  // 0..511
    for (int c = 0; c < NC; c++) {
        float m = memN_T[c * NA + a];
#pragma unroll
        for (int r = 0; r < 8; r++) acc[r] += xr[r][c] * m;
    }
#pragma unroll
    for (int r = 0; r < 8; r++) sim[(size_t)(g0 + r) * NA + a] = acc[r];
    float* tp = simT + ((size_t)(b * NA + a)) * NN + n0;
#pragma unroll
    for (int r = 0; r < 8; r++) tp[r] = acc[r];
}

// ---- sortable key: higher value wins, tie -> lower index (== lax.top_k order) ----
__device__ __forceinline__ unsigned long long pack_key(float v, unsigned idx) {
    unsigned u = __float_as_uint(v);
    u = (u & 0x80000000u) ? ~u : (u | 0x80000000u);
    return ((unsigned long long)u << 32) | (unsigned long long)(0xFFFFFFFFu - idx);
}

__device__ __forceinline__ void ins4(unsigned long long v, unsigned long long* k) {
    if (v > k[3]) {
        if (v > k[1]) {
            if (v > k[0]) { k[3] = k[2]; k[2] = k[1]; k[1] = k[0]; k[0] = v; }
            else         { k[3] = k[2]; k[2] = k[1]; k[1] = v; }
        } else {
            if (v > k[2]) { k[3] = k[2]; k[2] = v; }
            else          { k[3] = v; }
        }
    }
}

// butterfly merge of per-lane sorted-desc top-4 lists -> global top-4 in every lane
__device__ __forceinline__ void merge_top4(unsigned long long* k) {
#pragma unroll
    for (int d = 1; d < 64; d <<= 1) {
        unsigned long long p0 = __shfl_xor(k[0], d, 64);
        unsigned long long p1 = __shfl_xor(k[1], d, 64);
        unsigned long long p2 = __shfl_xor(k[2], d, 64);
        unsigned long long p3 = __shfl_xor(k[3], d, 64);
        unsigned long long c0 = k[0] > p3 ? k[0] : p3;
        unsigned long long c1 = k[1] > p2 ? k[1] : p2;
        unsigned long long c2 = k[2] > p1 ? k[2] : p1;
        unsigned long long c3 = k[3] > p0 ? k[3] : p0;
        unsigned long long d0 = c0 > c2 ? c0 : c2, d2 = c0 > c2 ? c2 : c0;
        unsigned long long d1 = c1 > c3 ? c1 : c3, d3 = c1 > c3 ? c3 : c1;
        k[0] = d0 > d1 ? d0 : d1; k[1] = d0 > d1 ? d1 : d0;
        k[2] = d2 > d3 ? d2 : d3; k[3] = d2 > d3 ? d3 : d2;
    }
}

// ---- fused top-4, both directions coalesced:
//   waves [0, B*N)        : knn rows over sim (512 wide)
//   waves [B*N, B*N+B*A)  : rev rows over simT (256 wide)
__global__ __launch_bounds__(256) void k_knnrev(const float* __restrict__ sim,
                                                const float* __restrict__ simT,
                                                int* __restrict__ knn,
                                                int* __restrict__ rev) {
    int wid = (blockIdx.x * 256 + threadIdx.x) >> 6;
    int lane = threadIdx.x & 63;
    unsigned long long k[4] = {0, 0, 0, 0};
    if (wid < NB * NN) {
        const float* row = sim + (size_t)wid * NA;
#pragma unroll
        for (int t = 0; t < NA / 64; t++) {
            int a = lane + 64 * t;
            ins4(pack_key(row[a], (unsigned)a), k);
        }
        merge_top4(k);
        if (lane < 4) knn[wid * 4 + lane] = (int)(0xFFFFFFFFu - (unsigned)k[lane]);
    } else {
        int w2 = wid - NB * NN;          // b*NA + a
        const float* row = simT + (size_t)w2 * NN;
#pragma unroll
        for (int t = 0; t < NN / 64; t++) {
            int n = lane + 64 * t;
            ins4(pack_key(row[n], (unsigned)n), k);
        }
        merge_top4(k);
        if (lane < 4) rev[w2 * 4 + lane] = (int)(0xFFFFFFFFu - (unsigned)k[lane]);
    }
}

// ---- fused W block builder:
//   blocks [0,1024)      : A x A mem block (batch-independent, broadcast to all b)
//   blocks [1024,3072)   : N x N adj block per batch
//   blocks [3072,5120)   : zero the off-diagonal N x A / A x N regions
__global__ __launch_bounds__(256) void k_wblocks(const float* __restrict__ mem_adj,
                                                 const float* __restrict__ dmem_inv,
                                                 const float* __restrict__ adj,
                                                 const float* __restrict__ sc_adj,
                                                 float* __restrict__ W) {
    __shared__ float ta[16][NK + 1];
    __shared__ float tb[16][NK + 1];
    int bi = blockIdx.x, tid = threadIdx.x;
    int tx = tid & 15, ty = tid >> 4;
    if (bi < 1024) {
        int a0 = (bi >> 5) * 16, a1 = (bi & 31) * 16;
        for (int i = tid; i < 16 * NK; i += 256) {
            int r = i / NK, j = i % NK;
            ta[r][j] = mem_adj[(a0 + r) * NK + j] * dmem_inv[j];
            tb[r][j] = mem_adj[(a1 + r) * NK + j];
        }
        __syncthreads();
        float s = 0.f;
        for (int j = 0; j < NK; j++) s += ta[ty][j] * tb[tx][j];
        int row = NN + a0 + ty, col = NN + a1 + tx;
        for (int b = 0; b < NB; b++) W[(size_t)b * NM * NM + (size_t)row * NM + col] = s;
    } else if (bi < 3072) {
        int t = bi - 1024;
        int n1 = (t & 15) * 16, n0 = ((t >> 4) & 15) * 16, b = t >> 8;
        const float* adjb = adj + (size_t)b * NN * NK;
        const float* scb = sc_adj + b * NK;
        for (int i = tid; i < 16 * NK; i += 256) {
            int r = i / NK, j = i % NK;
            ta[r][j] = adjb[(n0 + r) * NK + j] * scb[j];
            tb[r][j] = adjb[(n1 + r) * NK + j];
        }
        __syncthreads();
        float s = 0.f;
        for (int j = 0; j < NK; j++) s += ta[ty][j] * tb[tx][j];
        W[(size_t)b * NM * NM + (size_t)(n0 + ty) * NM + (n1 + tx)] = s;
    } else {
        int t = bi - 3072;               // [0, 2048)
        int b = t >> 8;
        int v = (t & 255) * 256 + tid;   // [0, 65536) float4 slots per batch
        int row, col4;
        if (v < 32768) { row = v >> 7; col4 = 64 + (v & 127); }      // rows 0..255, cols 256..767
        else { int v2 = v - 32768; row = 256 + (v2 >> 6); col4 = v2 & 63; }  // rows 256..767, cols 0..255
        f32x4 z; z[0] = 0.f; z[1] = 0.f; z[2] = 0.f; z[3] = 0.f;
        *(f32x4*)(W + (size_t)b * NM * NM + (size_t)row * NM + col4 * 4) = z;
    }
}

// ---- cross columns: each has exactly 5 ones (deg 5), 25-entry outer-product scatter ----
__global__ void k_scatter(const int* __restrict__ knn, const int* __restrict__ rev,
                          float* __restrict__ W) {
    int g = blockIdx.x * blockDim.x + threadIdx.x;  // b*NM + col
    if (g >= NB * NM) return;
    int b = g / NM, col = g % NM;
    const float cval = 1.0f / (5.0f + 1e-8f);
    int r[5];
    r[0] = col;
    if (col < NN) {
        const int* kk = knn + (size_t)(b * NN + col) * 4;
#pragma unroll
        for (int t = 0; t < 4; t++) r[t + 1] = NN + kk[t];
    } else {
        const int* rr = rev + (size_t)(b * NA + (col - NN)) * 4;
#pragma unroll
        for (int t = 0; t < 4; t++) r[t + 1] = rr[t];
    }
    float* Wb = W + (size_t)b * NM * NM;
#pragma unroll
    for (int i = 0; i < 5; i++)
#pragma unroll
        for (int j = 0; j < 5; j++) atomicAdd(&Wb[(size_t)r[i] * NM + r[j]], cval);
}

// ---- fused: W(f32) -> W16(bf16) + dis = 1/sqrt(rowsum+1+eps); one wave per row ----
__global__ __launch_bounds__(256) void k_w16dis(const float* __restrict__ W,
                                                unsigned short* __restrict__ W16,
                                                float* __restrict__ dis) {
    int wid = (blockIdx.x * 256 + threadIdx.x) >> 6;  // b*NM + row
    int lane = threadIdx.x & 63;
    if (wid >= NB * NM) return;
    const float* row = W + (size_t)wid * NM;
    unsigned short* row16 = W16 + (size_t)wid * NM;
    float s = 0.f;
#pragma unroll
    for (int t = 0; t < 3; t++) {
        int e = (lane + t * 64) * 4;
        f32x4 v = *(const f32x4*)(row + e);
        s += (v[0] + v[1]) + (v[2] + v[3]);
        u16x4 o;
        o[0] = f2bf(v[0]); o[1] = f2bf(v[1]); o[2] = f2bf(v[2]); o[3] = f2bf(v[3]);
        *(u16x4*)(row16 + e) = o;
    }
    s = wave_reduce_add(s);
    if (lane == 0) dis[wid] = 1.0f / sqrtf(s + 1.0f + 1e-8f);
}

// ---- Z0[b,c,m] = dis[b,m] * joint(b,c,m) (bf16); Xh[b,c,m] = 0.9 * joint ----
__global__ void k_y0(const float* __restrict__ feat, const float* __restrict__ tfT,
                     const float* __restrict__ dis, unsigned short* __restrict__ Z0,
                     float* __restrict__ Xh) {
    int bc = blockIdx.x;            // b*NC + c
    int b = bc >> 7, c = bc & 127;
    for (int m = threadIdx.x; m < NM; m += 256) {
        float v = (m < NN) ? feat[(size_t)bc * NN + m] : tfT[(size_t)c * NA + (m - NN)];
        Z0[(size_t)bc * NM + m] = f2bf(dis[b * NM + m] * v);
        Xh[(size_t)bc * NM + m] = 0.9f * v;
    }
}

// ---- MFMA propagation on Z = D^-1/2 Y:
//      s = W @ Zin ; o(=Y_next) = dis*(s + Zin) ; Xh += coef*o ; Zout = dis*o
__global__ __launch_bounds__(256) void k_prop(const unsigned short* __restrict__ W16,
                                              const float* __restrict__ dis,
                                              const unsigned short* __restrict__ Zin,
                                              unsigned short* __restrict__ Zout,
                                              float* __restrict__ Xh, float coef) {
    int b = blockIdx.z;
    int m0 = blockIdx.x * 32;   // 24 tiles
    int c0 = blockIdx.y * 64;   // 2 tiles
    int tid = threadIdx.x;
    int w = tid >> 6, l = tid & 63;
    int wm = w >> 1, wc = w & 1;
    int lr = l & 15, lg = l >> 4;

    const unsigned short* Ap = W16 + ((size_t)b * NM + m0 + wm * 16 + lr) * NM + lg * 8;
    const unsigned short* Bp = Zin + ((size_t)b * NC + c0 + wc * 32 + lr) * NM + lg * 8;

    f32x4 acc[2];
#pragma unroll
    for (int f = 0; f < 2; f++) { acc[f][0] = 0.f; acc[f][1] = 0.f; acc[f][2] = 0.f; acc[f][3] = 0.f; }

    bf16x8 a0 = *(const bf16x8*)(Ap);
    bf16x8 b0[2];
#pragma unroll
    for (int f = 0; f < 2; f++) b0[f] = *(const bf16x8*)(Bp + (size_t)(f * 16) * NM);

    for (int k0 = 0; k0 < NM - 32; k0 += 32) {
        bf16x8 a1 = *(const bf16x8*)(Ap + k0 + 32);
        bf16x8 b1[2];
#pragma unroll
        for (int f = 0; f < 2; f++) b1[f] = *(const bf16x8*)(Bp + (size_t)(f * 16) * NM + k0 + 32);
#pragma unroll
        for (int f = 0; f < 2; f++)
            acc[f] = __builtin_amdgcn_mfma_f32_16x16x32_bf16(a0, b0[f], acc[f], 0, 0, 0);
        a0 = a1;
#pragma unroll
        for (int f = 0; f < 2; f++) b0[f] = b1[f];
    }
#pragma unroll
    for (int f = 0; f < 2; f++)
        acc[f] = __builtin_amdgcn_mfma_f32_16x16x32_bf16(a0, b0[f], acc[f], 0, 0, 0);

    // epilogue: lane holds D[row=lg*4+r][col=lr] per frag f
    int mb = m0 + wm * 16 + lg * 4;
    f32x4 dv = *(const f32x4*)(dis + b * NM + mb);
#pragma unroll
    for (int f = 0; f < 2; f++) {
        int c = c0 + wc * 32 + f * 16 + lr;
        size_t off = ((size_t)b * NC + c) * NM + mb;
        u16x4 zi = *(const u16x4*)(Zin + off);
        f32x4 xh = *(const f32x4*)(Xh + off);
        u16x4 zo;
#pragma unroll
        for (int r = 0; r < 4; r++) {
            float o = dv[r] * (acc[f][r] + bf2f(zi[r]));
            xh[r] += coef * o;
            zo[r] = f2bf(dv[r] * o);
        }
        *(f32x4*)(Xh + off) = xh;
        *(u16x4*)(Zout + off) = zo;
    }
}

// ---- fused outputs:
//   blocks [0,1024)   : X_hat (B,C,N) = Xh[:, :, :N]  (contiguous row copy)
//   blocks [1024,1408): X_E tiled GEMM
__global__ __launch_bounds__(256) void k_out(const float* __restrict__ Xh,
                                             const float* __restrict__ adj,
                                             const float* __restrict__ isn,
                                             const float* __restrict__ inv_edge,
                                             float* __restrict__ out_xhat,
                                             float* __restrict__ outE) {
    __shared__ float ta[16][17];  // [n_local][k_local]
    __shared__ float tz[16][17];  // [c_local][n_local]
    int bi = blockIdx.x;
    if (bi < 1024) {              // b*NC + c
        int n = threadIdx.x;
        out_xhat[(size_t)bi * NN + n] = Xh[(size_t)bi * NM + n];
        return;
    }
    int t = bi - 1024;            // [0, 384)
    int b = t / 48;
    int r = t % 48;
    int k0 = (r >> 3) * 16;       // 6 tiles
    int c0 = (r & 7) * 16;        // 8 tiles
    int tx = threadIdx.x & 15;
    int ty = threadIdx.x >> 4;
    float acc = 0.f;
    for (int n0 = 0; n0 < NN; n0 += 16) {
        int n = n0 + ty;
        ta[ty][tx] = adj[(size_t)(b * NN + n) * NK + k0 + tx] * isn[b * NN + n];
        tz[ty][tx] = Xh[((size_t)b * NC + c0 + ty) * NM + n0 + tx];
        __syncthreads();
#pragma unroll
        for (int nn = 0; nn < 16; nn++) acc += ta[nn][ty] * tz[tx][nn];
        __syncthreads();
    }
    int k = k0 + ty, c = c0 + tx;
    outE[(size_t)(b * NK + k) * NC + c] = inv_edge[b * NK + k] * acc;
}

extern "C" void kernel_launch(void* const* d_in, const int* in_sizes, int n_in,
                              void* d_out, int out_size, void* d_ws, size_t ws_size,
                              hipStream_t stream) {
    (void)in_sizes; (void)n_in; (void)out_size; (void)ws_size;
    const float* features = (const float*)d_in[0];  // (B,C,N)
    const float* adj      = (const float*)d_in[1];  // (B,N,K)
    const float* tf       = (const float*)d_in[2];  // (A,C)
    const float* mem_adj  = (const float*)d_in[3];  // (A,K)
    float* out_xhat = (float*)d_out;                 // (B,C,N)
    float* out_xe   = out_xhat + (size_t)NB * NC * NN;  // (B,K,C)

    float* p = (float*)d_ws;
    float* memN_T  = p; p += (size_t)NC * NA;
    float* tfT     = p; p += (size_t)NC * NA;
    float* Xn      = p; p += (size_t)NB * NN * NC;
    float* sim     = p; p += (size_t)NB * NN * NA;
    float* simT    = p; p += (size_t)NB * NN * NA;
    float* sc_adj  = p; p += NB * NK;
    float* inv_edge= p; p += NB * NK;
    float* dmem_inv= p; p += NK;
    float* isn     = p; p += NB * NN;
    float* dis     = p; p += NB * NM;
    float* W       = p; p += (size_t)NB * NM * NM;
    float* Xh      = p; p += (size_t)NB * NC * NM;   // (B,C,M) f32
    unsigned short* W16 = (unsigned short*)p;        // (B,M,M) bf16
    unsigned short* Z0  = W16 + (size_t)NB * NM * NM;
    unsigned short* Z1  = Z0 + (size_t)NB * NC * NM;
    int* knn = (int*)(Z1 + (size_t)NB * NC * NM);
    int* rev = knn + NB * NN * 4;

    k_normdeg<<<NORM_BLKS + (DEG_WAVES + 1) / 2, 128, 0, stream>>>(
        tf, features, mem_adj, adj, memN_T, tfT, Xn, dmem_inv, sc_adj, inv_edge, isn);
    k_sim<<<NB * NN / 8, 512, 0, stream>>>(Xn, memN_T, sim, simT);
    k_knnrev<<<(NB * NN + NB * NA) / 4, 256, 0, stream>>>(sim, simT, knn, rev);
    k_wblocks<<<5120, 256, 0, stream>>>(mem_adj, dmem_inv, adj, sc_adj, W);
    k_scatter<<<NB * NM / 256, 256, 0, stream>>>(knn, rev, W);
    k_w16dis<<<NB * NM / 4, 256, 0, stream>>>(W, W16, dis);
    k_y0<<<NB * NC, 256, 0, stream>>>(features, tfT, dis, Z0, Xh);
    dim3 pg(NM / 32, NC / 64, NB);
    k_prop<<<pg, 256, 0, stream>>>(W16, dis, Z0, Z1, Xh, 0.09f);
    k_prop<<<pg, 256, 0, stream>>>(W16, dis, Z1, Z0, Xh, 0.009f);
    k_prop<<<pg, 256, 0, stream>>>(W16, dis, Z0, Z1, Xh, 0.001f);
    k_out<<<1024 + 384, 256, 0, stream>>>(Xh, adj, isn, inv_edge, out_xhat, out_xe);
}

// Round 8
// 118.778 us; speedup vs baseline: 6.8573x; 1.1533x over previous
//
#include <hip/hip_runtime.h>

#define NB 8
#define NC 128
#define NN 256
#define NK 96
#define NA 512
#define NM 768   // NN + NA

typedef __attribute__((ext_vector_type(8))) short bf16x8;
typedef __attribute__((ext_vector_type(4))) float f32x4;
typedef __attribute__((ext_vector_type(4))) unsigned short u16x4;

__device__ __forceinline__ float wave_reduce_add(float s) {
    for (int o = 32; o > 0; o >>= 1) s += __shfl_down(s, o, 64);
    return s;
}

// f32 -> bf16 round-to-nearest-even
__device__ __forceinline__ unsigned short f2bf(float x) {
    unsigned u = __float_as_uint(x);
    unsigned r = (u + 0x7FFFu + ((u >> 16) & 1u)) >> 16;
    return (unsigned short)r;
}
__device__ __forceinline__ float bf2f(unsigned short h) {
    return __uint_as_float((unsigned)h << 16);
}

// ---- fused normalize + degrees (128 threads/block)
#define NORM_BLKS (NA + NB * NN)
#define DEG_WAVES (NK + NB * NK + NB * NN)
__global__ __launch_bounds__(128) void k_normdeg(const float* __restrict__ tf,
                                                 const float* __restrict__ feat,
                                                 const float* __restrict__ mem_adj,
                                                 const float* __restrict__ adj,
                                                 float* __restrict__ memN_T,
                                                 float* __restrict__ tfT,
                                                 float* __restrict__ Xn,
                                                 float* __restrict__ dmem_inv,
                                                 float* __restrict__ sc_adj,
                                                 float* __restrict__ inv_edge,
                                                 float* __restrict__ isn) {
    __shared__ float p[2];
    int bi = blockIdx.x, c = threadIdx.x;
    if (bi < NA) {
        int a = bi;
        float v = tf[a * NC + c];
        float s = wave_reduce_add(v * v);
        if ((c & 63) == 0) p[c >> 6] = s;
        __syncthreads();
        float norm = sqrtf(p[0] + p[1]);
        memN_T[c * NA + a] = v / fmaxf(norm, 1e-12f);
        tfT[c * NA + a] = v;
    } else if (bi < NORM_BLKS) {
        int g = bi - NA;                 // b*NN + n
        int b = g >> 8, n = g & 255;
        float v = feat[(b * NC + c) * NN + n];
        float s = wave_reduce_add(v * v);
        if ((c & 63) == 0) p[c >> 6] = s;
        __syncthreads();
        float norm = sqrtf(p[0] + p[1]);
        Xn[g * NC + c] = v / fmaxf(norm, 1e-12f);
    } else {
        int wid = (bi - NORM_BLKS) * 2 + (c >> 6);
        int lane = c & 63;
        if (wid < NK) {
            float s = 0.f;
            for (int a = lane; a < NA; a += 64) s += mem_adj[(size_t)a * NK + wid];
            s = wave_reduce_add(s);
            if (lane == 0) dmem_inv[wid] = 1.0f / (s + 1e-8f);
        } else if (wid < NK + NB * NK) {
            int w2 = wid - NK;
            int b = w2 / NK, k = w2 % NK;
            float s = 0.f;
            for (int n = lane; n < NN; n += 64) s += adj[(size_t)(b * NN + n) * NK + k];
            s = wave_reduce_add(s);
            if (lane == 0) {
                sc_adj[w2] = 1.0f / (s + 1e-8f);
                inv_edge[w2] = 1.0f / fmaxf(s, 1e-8f);
            }
        } else if (wid < DEG_WAVES) {
            int w3 = wid - NK - NB * NK;     // b*NN + n
            const float* row = adj + (size_t)w3 * NK;
            float s = (lane < NK) ? row[lane] : 0.f;
            if (lane + 64 < NK) s += row[lane + 64];   // NK=96
            s = wave_reduce_add(s);
            if (lane == 0) isn[w3] = 1.0f / sqrtf(fmaxf(s, 1e-8f));
        }
    }
}

// ---- cosine similarity; writes n-major sim AND a-major simT (vectorized) ----
__global__ __launch_bounds__(512) void k_sim(const float* __restrict__ Xn,
                                             const float* __restrict__ memN_T,
                                             float* __restrict__ sim,
                                             float* __restrict__ simT) {
    __shared__ float xr[8][NC];
    int g0 = blockIdx.x * 8;
    int b = g0 >> 8, n0 = g0 & 255;
    int t = threadIdx.x;
    for (int i = t; i < 8 * NC; i += 512) xr[i / NC][i % NC] = Xn[g0 * NC + i];
    __syncthreads();
    float acc[8] = {0, 0, 0, 0, 0, 0, 0, 0};
    int a = t;  // 0..511
    for (int c = 0; c < NC; c++) {
        float m = memN_T[c * NA + a];
#pragma unroll
        for (int r = 0; r < 8; r++) acc[r] += xr[r][c] * m;
    }
#pragma unroll
    for (int r = 0; r < 8; r++) sim[(size_t)(g0 + r) * NA + a] = acc[r];
    float* tp = simT + ((size_t)(b * NA + a)) * NN + n0;
    f32x4 v0, v1;
    v0[0] = acc[0]; v0[1] = acc[1]; v0[2] = acc[2]; v0[3] = acc[3];
    v1[0] = acc[4]; v1[1] = acc[5]; v1[2] = acc[6]; v1[3] = acc[7];
    *(f32x4*)tp = v0;
    *(f32x4*)(tp + 4) = v1;
}

// ---- sortable key: higher value wins, tie -> lower index (== lax.top_k order) ----
__device__ __forceinline__ unsigned long long pack_key(float v, unsigned idx) {
    unsigned u = __float_as_uint(v);
    u = (u & 0x80000000u) ? ~u : (u | 0x80000000u);
    return ((unsigned long long)u << 32) | (unsigned long long)(0xFFFFFFFFu - idx);
}

__device__ __forceinline__ void ins4(unsigned long long v, unsigned long long* k) {
    if (v > k[3]) {
        if (v > k[1]) {
            if (v > k[0]) { k[3] = k[2]; k[2] = k[1]; k[1] = k[0]; k[0] = v; }
            else         { k[3] = k[2]; k[2] = k[1]; k[1] = v; }
        } else {
            if (v > k[2]) { k[3] = k[2]; k[2] = v; }
            else          { k[3] = v; }
        }
    }
}

__device__ __forceinline__ void merge_top4(unsigned long long* k) {
#pragma unroll
    for (int d = 1; d < 64; d <<= 1) {
        unsigned long long p0 = __shfl_xor(k[0], d, 64);
        unsigned long long p1 = __shfl_xor(k[1], d, 64);
        unsigned long long p2 = __shfl_xor(k[2], d, 64);
        unsigned long long p3 = __shfl_xor(k[3], d, 64);
        unsigned long long c0 = k[0] > p3 ? k[0] : p3;
        unsigned long long c1 = k[1] > p2 ? k[1] : p2;
        unsigned long long c2 = k[2] > p1 ? k[2] : p1;
        unsigned long long c3 = k[3] > p0 ? k[3] : p0;
        unsigned long long d0 = c0 > c2 ? c0 : c2, d2 = c0 > c2 ? c2 : c0;
        unsigned long long d1 = c1 > c3 ? c1 : c3, d3 = c1 > c3 ? c3 : c1;
        k[0] = d0 > d1 ? d0 : d1; k[1] = d0 > d1 ? d1 : d0;
        k[2] = d2 > d3 ? d2 : d3; k[3] = d2 > d3 ? d3 : d2;
    }
}

// ---- fused top-4 + cross-column scatter (runs AFTER k_wblocks):
//   waves [0, B*N)        : knn rows over sim, scatter 25-entry clique
//   waves [B*N, B*N+B*A)  : rev rows over simT, scatter 25-entry clique
__global__ __launch_bounds__(256) void k_knnrev(const float* __restrict__ sim,
                                                const float* __restrict__ simT,
                                                float* __restrict__ W) {
    int wid = (blockIdx.x * 256 + threadIdx.x) >> 6;
    int lane = threadIdx.x & 63;
    unsigned long long k[4] = {0, 0, 0, 0};
    const float cval = 1.0f / (5.0f + 1e-8f);
    int b, rr0;
    if (wid < NB * NN) {
        b = wid >> 8;
        rr0 = wid & 255;                     // test col: r[0]=n, r[1..4]=NN+topk(mem)
        const float* row = sim + (size_t)wid * NA;
#pragma unroll
        for (int t = 0; t < NA / 64; t++) {
            int a = lane + 64 * t;
            ins4(pack_key(row[a], (unsigned)a), k);
        }
        merge_top4(k);
        int rr[5];
        rr[0] = rr0;
#pragma unroll
        for (int t = 0; t < 4; t++) rr[t + 1] = NN + (int)(0xFFFFFFFFu - (unsigned)k[t]);
        if (lane < 25) {
            int i = lane / 5, j = lane - i * 5;
            atomicAdd(W + (size_t)b * NM * NM + (size_t)rr[i] * NM + rr[j], cval);
        }
    } else {
        int w2 = wid - NB * NN;              // b*NA + a
        b = w2 >> 9;
        rr0 = NN + (w2 & 511);               // mem col: r[0]=NN+a, r[1..4]=topk(test)
        const float* row = simT + (size_t)w2 * NN;
#pragma unroll
        for (int t = 0; t < NN / 64; t++) {
            int n = lane + 64 * t;
            ins4(pack_key(row[n], (unsigned)n), k);
        }
        merge_top4(k);
        int rr[5];
        rr[0] = rr0;
#pragma unroll
        for (int t = 0; t < 4; t++) rr[t + 1] = (int)(0xFFFFFFFFu - (unsigned)k[t]);
        if (lane < 25) {
            int i = lane / 5, j = lane - i * 5;
            atomicAdd(W + (size_t)b * NM * NM + (size_t)rr[i] * NM + rr[j], cval);
        }
    }
}

// ---- fused W block builder:
//   blocks [0,1024)      : A x A mem block (batch-independent, broadcast to all b)
//   blocks [1024,3072)   : N x N adj block per batch
//   blocks [3072,3584)   : zero the off-diagonal N x A / A x N regions (4 f32x4/thread)
__global__ __launch_bounds__(256) void k_wblocks(const float* __restrict__ mem_adj,
                                                 const float* __restrict__ dmem_inv,
                                                 const float* __restrict__ adj,
                                                 const float* __restrict__ sc_adj,
                                                 float* __restrict__ W) {
    __shared__ float ta[16][NK + 1];
    __shared__ float tb[16][NK + 1];
    int bi = blockIdx.x, tid = threadIdx.x;
    int tx = tid & 15, ty = tid >> 4;
    if (bi < 1024) {
        int a0 = (bi >> 5) * 16, a1 = (bi & 31) * 16;
        for (int i = tid; i < 16 * NK; i += 256) {
            int r = i / NK, j = i % NK;
            ta[r][j] = mem_adj[(a0 + r) * NK + j] * dmem_inv[j];
            tb[r][j] = mem_adj[(a1 + r) * NK + j];
        }
        __syncthreads();
        float s = 0.f;
        for (int j = 0; j < NK; j++) s += ta[ty][j] * tb[tx][j];
        int row = NN + a0 + ty, col = NN + a1 + tx;
        for (int b = 0; b < NB; b++) W[(size_t)b * NM * NM + (size_t)row * NM + col] = s;
    } else if (bi < 3072) {
        int t = bi - 1024;
        int n1 = (t & 15) * 16, n0 = ((t >> 4) & 15) * 16, b = t >> 8;
        const float* adjb = adj + (size_t)b * NN * NK;
        const float* scb = sc_adj + b * NK;
        for (int i = tid; i < 16 * NK; i += 256) {
            int r = i / NK, j = i % NK;
            ta[r][j] = adjb[(n0 + r) * NK + j] * scb[j];
            tb[r][j] = adjb[(n1 + r) * NK + j];
        }
        __syncthreads();
        float s = 0.f;
        for (int j = 0; j < NK; j++) s += ta[ty][j] * tb[tx][j];
        W[(size_t)b * NM * NM + (size_t)(n0 + ty) * NM + (n1 + tx)] = s;
    } else {
        int t = bi - 3072;               // [0, 512)
        int b = t >> 6;
        f32x4 z; z[0] = 0.f; z[1] = 0.f; z[2] = 0.f; z[3] = 0.f;
#pragma unroll
        for (int q = 0; q < 4; q++) {
            int v = (t & 63) * 1024 + q * 256 + tid;   // [0, 65536) float4 slots per batch
            int row, col4;
            if (v < 32768) { row = v >> 7; col4 = 64 + (v & 127); }      // rows 0..255, cols 256..767
            else { int v2 = v - 32768; row = 256 + (v2 >> 6); col4 = v2 & 63; }
            *(f32x4*)(W + (size_t)b * NM * NM + (size_t)row * NM + col4 * 4) = z;
        }
    }
}

// ---- fused: W(f32) -> W16(bf16) + dis = 1/sqrt(rowsum+1+eps); one wave per row ----
__global__ __launch_bounds__(256) void k_w16dis(const float* __restrict__ W,
                                                unsigned short* __restrict__ W16,
                                                float* __restrict__ dis) {
    int wid = (blockIdx.x * 256 + threadIdx.x) >> 6;  // b*NM + row
    int lane = threadIdx.x & 63;
    if (wid >= NB * NM) return;
    const float* row = W + (size_t)wid * NM;
    unsigned short* row16 = W16 + (size_t)wid * NM;
    float s = 0.f;
#pragma unroll
    for (int t = 0; t < 3; t++) {
        int e = (lane + t * 64) * 4;
        f32x4 v = *(const f32x4*)(row + e);
        s += (v[0] + v[1]) + (v[2] + v[3]);
        u16x4 o;
        o[0] = f2bf(v[0]); o[1] = f2bf(v[1]); o[2] = f2bf(v[2]); o[3] = f2bf(v[3]);
        *(u16x4*)(row16 + e) = o;
    }
    s = wave_reduce_add(s);
    if (lane == 0) dis[wid] = 1.0f / sqrtf(s + 1.0f + 1e-8f);
}

// ---- Z0[b,c,m] = dis[b,m] * joint(b,c,m) (bf16); Xh[b,c,m] = 0.9 * joint ----
__global__ void k_y0(const float* __restrict__ feat, const float* __restrict__ tfT,
                     const float* __restrict__ dis, unsigned short* __restrict__ Z0,
                     float* __restrict__ Xh) {
    int bc = blockIdx.x;            // b*NC + c
    int b = bc >> 7, c = bc & 127;
    for (int m = threadIdx.x; m < NM; m += 256) {
        float v = (m < NN) ? feat[(size_t)bc * NN + m] : tfT[(size_t)c * NA + (m - NN)];
        Z0[(size_t)bc * NM + m] = f2bf(dis[b * NM + m] * v);
        Xh[(size_t)bc * NM + m] = 0.9f * v;
    }
}

// ---- MFMA propagation on Z = D^-1/2 Y (full step):
//      s = W @ Zin ; o = dis*(s + Zin) ; Xh += coef*o ; Zout = dis*o
__global__ __launch_bounds__(256) void k_prop(const unsigned short* __restrict__ W16,
                                              const float* __restrict__ dis,
                                              const unsigned short* __restrict__ Zin,
                                              unsigned short* __restrict__ Zout,
                                              float* __restrict__ Xh, float coef) {
    int b = blockIdx.z;
    int m0 = blockIdx.x * 32;   // 24 tiles
    int c0 = blockIdx.y * 64;   // 2 tiles
    int tid = threadIdx.x;
    int w = tid >> 6, l = tid & 63;
    int wm = w >> 1, wc = w & 1;
    int lr = l & 15, lg = l >> 4;

    const unsigned short* Ap = W16 + ((size_t)b * NM + m0 + wm * 16 + lr) * NM + lg * 8;
    const unsigned short* Bp = Zin + ((size_t)b * NC + c0 + wc * 32 + lr) * NM + lg * 8;

    f32x4 acc[2];
#pragma unroll
    for (int f = 0; f < 2; f++) { acc[f][0] = 0.f; acc[f][1] = 0.f; acc[f][2] = 0.f; acc[f][3] = 0.f; }

    bf16x8 a0 = *(const bf16x8*)(Ap);
    bf16x8 b0[2];
#pragma unroll
    for (int f = 0; f < 2; f++) b0[f] = *(const bf16x8*)(Bp + (size_t)(f * 16) * NM);

    for (int k0 = 0; k0 < NM - 32; k0 += 32) {
        bf16x8 a1 = *(const bf16x8*)(Ap + k0 + 32);
        bf16x8 b1[2];
#pragma unroll
        for (int f = 0; f < 2; f++) b1[f] = *(const bf16x8*)(Bp + (size_t)(f * 16) * NM + k0 + 32);
#pragma unroll
        for (int f = 0; f < 2; f++)
            acc[f] = __builtin_amdgcn_mfma_f32_16x16x32_bf16(a0, b0[f], acc[f], 0, 0, 0);
        a0 = a1;
#pragma unroll
        for (int f = 0; f < 2; f++) b0[f] = b1[f];
    }
#pragma unroll
    for (int f = 0; f < 2; f++)
        acc[f] = __builtin_amdgcn_mfma_f32_16x16x32_bf16(a0, b0[f], acc[f], 0, 0, 0);

    int mb = m0 + wm * 16 + lg * 4;
    f32x4 dv = *(const f32x4*)(dis + b * NM + mb);
#pragma unroll
    for (int f = 0; f < 2; f++) {
        int c = c0 + wc * 32 + f * 16 + lr;
        size_t off = ((size_t)b * NC + c) * NM + mb;
        u16x4 zi = *(const u16x4*)(Zin + off);
        f32x4 xh = *(const f32x4*)(Xh + off);
        u16x4 zo;
#pragma unroll
        for (int r = 0; r < 4; r++) {
            float o = dv[r] * (acc[f][r] + bf2f(zi[r]));
            xh[r] += coef * o;
            zo[r] = f2bf(dv[r] * o);
        }
        *(f32x4*)(Xh + off) = xh;
        *(u16x4*)(Zout + off) = zo;
    }
}

// ---- last propagation: only m<256 matters; writes X_hat (B,C,N) directly ----
__global__ __launch_bounds__(256) void k_prop_last(const unsigned short* __restrict__ W16,
                                                   const float* __restrict__ dis,
                                                   const unsigned short* __restrict__ Zin,
                                                   const float* __restrict__ Xh,
                                                   float* __restrict__ out_xhat, float coef) {
    int b = blockIdx.z;
    int m0 = blockIdx.x * 32;   // 8 tiles -> m < 256
    int c0 = blockIdx.y * 64;
    int tid = threadIdx.x;
    int w = tid >> 6, l = tid & 63;
    int wm = w >> 1, wc = w & 1;
    int lr = l & 15, lg = l >> 4;

    const unsigned short* Ap = W16 + ((size_t)b * NM + m0 + wm * 16 + lr) * NM + lg * 8;
    const unsigned short* Bp = Zin + ((size_t)b * NC + c0 + wc * 32 + lr) * NM + lg * 8;

    f32x4 acc[2];
#pragma unroll
    for (int f = 0; f < 2; f++) { acc[f][0] = 0.f; acc[f][1] = 0.f; acc[f][2] = 0.f; acc[f][3] = 0.f; }

    bf16x8 a0 = *(const bf16x8*)(Ap);
    bf16x8 b0[2];
#pragma unroll
    for (int f = 0; f < 2; f++) b0[f] = *(const bf16x8*)(Bp + (size_t)(f * 16) * NM);

    for (int k0 = 0; k0 < NM - 32; k0 += 32) {
        bf16x8 a1 = *(const bf16x8*)(Ap + k0 + 32);
        bf16x8 b1[2];
#pragma unroll
        for (int f = 0; f < 2; f++) b1[f] = *(const bf16x8*)(Bp + (size_t)(f * 16) * NM + k0 + 32);
#pragma unroll
        for (int f = 0; f < 2; f++)
            acc[f] = __builtin_amdgcn_mfma_f32_16x16x32_bf16(a0, b0[f], acc[f], 0, 0, 0);
        a0 = a1;
#pragma unroll
        for (int f = 0; f < 2; f++) b0[f] = b1[f];
    }
#pragma unroll
    for (int f = 0; f < 2; f++)
        acc[f] = __builtin_amdgcn_mfma_f32_16x16x32_bf16(a0, b0[f], acc[f], 0, 0, 0);

    int mb = m0 + wm * 16 + lg * 4;   // < 256
    f32x4 dv = *(const f32x4*)(dis + b * NM + mb);
#pragma unroll
    for (int f = 0; f < 2; f++) {
        int c = c0 + wc * 32 + f * 16 + lr;
        size_t offM = ((size_t)b * NC + c) * NM + mb;
        u16x4 zi = *(const u16x4*)(Zin + offM);
        f32x4 xh = *(const f32x4*)(Xh + offM);
        f32x4 ov;
#pragma unroll
        for (int r = 0; r < 4; r++) {
            float o = dv[r] * (acc[f][r] + bf2f(zi[r]));
            ov[r] = xh[r] + coef * o;
        }
        *(f32x4*)(out_xhat + ((size_t)b * NC + c) * NN + mb) = ov;
    }
}

// ---- X_E[b,k,c] = inv_edge[b,k] * sum_n (adj[b,n,k]*isn[b,n]) * Xhat[b,c,n] ----
__global__ __launch_bounds__(256) void k_xe(const float* __restrict__ Xhat,
                                            const float* __restrict__ adj,
                                            const float* __restrict__ isn,
                                            const float* __restrict__ inv_edge,
                                            float* __restrict__ outE) {
    __shared__ float ta[16][17];  // [n_local][k_local]
    __shared__ float tz[16][17];  // [c_local][n_local]
    int b = blockIdx.z;
    int k0 = blockIdx.y * 16;     // 6 tiles
    int c0 = blockIdx.x * 16;     // 8 tiles
    int tx = threadIdx.x & 15;
    int ty = threadIdx.x >> 4;
    float acc = 0.f;
    for (int n0 = 0; n0 < NN; n0 += 16) {
        int n = n0 + ty;
        ta[ty][tx] = adj[(size_t)(b * NN + n) * NK + k0 + tx] * isn[b * NN + n];
        tz[ty][tx] = Xhat[((size_t)b * NC + c0 + ty) * NN + n0 + tx];
        __syncthreads();
#pragma unroll
        for (int nn = 0; nn < 16; nn++) acc += ta[nn][ty] * tz[tx][nn];
        __syncthreads();
    }
    int k = k0 + ty, c = c0 + tx;
    outE[(size_t)(b * NK + k) * NC + c] = inv_edge[b * NK + k] * acc;
}

extern "C" void kernel_launch(void* const* d_in, const int* in_sizes, int n_in,
                              void* d_out, int out_size, void* d_ws, size_t ws_size,
                              hipStream_t stream) {
    (void)in_sizes; (void)n_in; (void)out_size; (void)ws_size;
    const float* features = (const float*)d_in[0];  // (B,C,N)
    const float* adj      = (const float*)d_in[1];  // (B,N,K)
    const float* tf       = (const float*)d_in[2];  // (A,C)
    const float* mem_adj  = (const float*)d_in[3];  // (A,K)
    float* out_xhat = (float*)d_out;                 // (B,C,N)
    float* out_xe   = out_xhat + (size_t)NB * NC * NN;  // (B,K,C)

    float* p = (float*)d_ws;
    float* memN_T  = p; p += (size_t)NC * NA;
    float* tfT     = p; p += (size_t)NC * NA;
    float* Xn      = p; p += (size_t)NB * NN * NC;
    float* sim     = p; p += (size_t)NB * NN * NA;
    float* simT    = p; p += (size_t)NB * NN * NA;
    float* sc_adj  = p; p += NB * NK;
    float* inv_edge= p; p += NB * NK;
    float* dmem_inv= p; p += NK;
    float* isn     = p; p += NB * NN;
    float* dis     = p; p += NB * NM;
    float* W       = p; p += (size_t)NB * NM * NM;
    float* Xh      = p; p += (size_t)NB * NC * NM;   // (B,C,M) f32
    unsigned short* W16 = (unsigned short*)p;        // (B,M,M) bf16
    unsigned short* Z0  = W16 + (size_t)NB * NM * NM;
    unsigned short* Z1  = Z0 + (size_t)NB * NC * NM;

    k_normdeg<<<NORM_BLKS + (DEG_WAVES + 1) / 2, 128, 0, stream>>>(
        tf, features, mem_adj, adj, memN_T, tfT, Xn, dmem_inv, sc_adj, inv_edge, isn);
    k_sim<<<NB * NN / 8, 512, 0, stream>>>(Xn, memN_T, sim, simT);
    k_wblocks<<<3584, 256, 0, stream>>>(mem_adj, dmem_inv, adj, sc_adj, W);
    k_knnrev<<<(NB * NN + NB * NA) / 4, 256, 0, stream>>>(sim, simT, W);
    k_w16dis<<<NB * NM / 4, 256, 0, stream>>>(W, W16, dis);
    k_y0<<<NB * NC, 256, 0, stream>>>(features, tfT, dis, Z0, Xh);
    dim3 pg(NM / 32, NC / 64, NB);
    k_prop<<<pg, 256, 0, stream>>>(W16, dis, Z0, Z1, Xh, 0.09f);
    k_prop<<<pg, 256, 0, stream>>>(W16, dis, Z1, Z0, Xh, 0.009f);
    dim3 pl(NN / 32, NC / 64, NB);
    k_prop_last<<<pl, 256, 0, stream>>>(W16, dis, Z0, Xh, out_xhat, 0.001f);
    k_xe<<<dim3(NC / 16, NK / 16, NB), 256, 0, stream>>>(out_xhat, adj, isn, inv_edge, out_xe);
}

// Round 11
// 109.577 us; speedup vs baseline: 7.4331x; 1.0840x over previous
//
#include <hip/hip_runtime.h>

#define NB 8
#define NC 128
#define NN 256
#define NK 96
#define NA 512
#define NM 768   // NN + NA

typedef __attribute__((ext_vector_type(8))) short bf16x8;
typedef __attribute__((ext_vector_type(4))) float f32x4;
typedef __attribute__((ext_vector_type(4))) unsigned short u16x4;

__device__ __forceinline__ float wave_reduce_add(float s) {
    for (int o = 32; o > 0; o >>= 1) s += __shfl_down(s, o, 64);
    return s;
}

// f32 -> bf16 round-to-nearest-even
__device__ __forceinline__ unsigned short f2bf(float x) {
    unsigned u = __float_as_uint(x);
    unsigned r = (u + 0x7FFFu + ((u >> 16) & 1u)) >> 16;
    return (unsigned short)r;
}
__device__ __forceinline__ float bf2f(unsigned short h) {
    return __uint_as_float((unsigned)h << 16);
}

// ---- fused normalize + degrees (128 threads/block) ----
#define NORM_BLKS (NA + NB * NN)
#define DEG_WAVES (NK + NB * NK + NB * NN)
__global__ __launch_bounds__(128) void k_normdeg(const float* __restrict__ tf,
                                                 const float* __restrict__ feat,
                                                 const float* __restrict__ mem_adj,
                                                 const float* __restrict__ adj,
                                                 float* __restrict__ memN_T,
                                                 float* __restrict__ tfT,
                                                 float* __restrict__ Xn,
                                                 float* __restrict__ dmem_inv,
                                                 float* __restrict__ sc_adj,
                                                 float* __restrict__ inv_edge,
                                                 float* __restrict__ isn) {
    __shared__ float p[2];
    int bi = blockIdx.x, c = threadIdx.x;
    if (bi < NA) {
        int a = bi;
        float v = tf[a * NC + c];
        float s = wave_reduce_add(v * v);
        if ((c & 63) == 0) p[c >> 6] = s;
        __syncthreads();
        float norm = sqrtf(p[0] + p[1]);
        memN_T[c * NA + a] = v / fmaxf(norm, 1e-12f);
        tfT[c * NA + a] = v;
    } else if (bi < NORM_BLKS) {
        int g = bi - NA;                 // b*NN + n
        int b = g >> 8, n = g & 255;
        float v = feat[(b * NC + c) * NN + n];
        float s = wave_reduce_add(v * v);
        if ((c & 63) == 0) p[c >> 6] = s;
        __syncthreads();
        float norm = sqrtf(p[0] + p[1]);
        Xn[g * NC + c] = v / fmaxf(norm, 1e-12f);
    } else {
        int wid = (bi - NORM_BLKS) * 2 + (c >> 6);
        int lane = c & 63;
        if (wid < NK) {
            float s = 0.f;
            for (int a = lane; a < NA; a += 64) s += mem_adj[(size_t)a * NK + wid];
            s = wave_reduce_add(s);
            if (lane == 0) dmem_inv[wid] = 1.0f / (s + 1e-8f);
        } else if (wid < NK + NB * NK) {
            int w2 = wid - NK;
            int b = w2 / NK, k = w2 % NK;
            float s = 0.f;
            for (int n = lane; n < NN; n += 64) s += adj[(size_t)(b * NN + n) * NK + k];
            s = wave_reduce_add(s);
            if (lane == 0) {
                sc_adj[w2] = 1.0f / (s + 1e-8f);
                inv_edge[w2] = 1.0f / fmaxf(s, 1e-8f);
            }
        } else if (wid < DEG_WAVES) {
            int w3 = wid - NK - NB * NK;     // b*NN + n
            const float* row = adj + (size_t)w3 * NK;
            float s = (lane < NK) ? row[lane] : 0.f;
            if (lane + 64 < NK) s += row[lane + 64];   // NK=96
            s = wave_reduce_add(s);
            if (lane == 0) isn[w3] = 1.0f / sqrtf(fmaxf(s, 1e-8f));
        }
    }
}

// ---- fused: similarity (+transpose) AND W block builder AND off-diag zero ----
//   blocks [0,256)       : sim rows (8 n-rows x 512 a, 2 a per thread) -> sim, simT
//   blocks [256,1280)    : A x A mem block (batch-independent, broadcast to all b)
//   blocks [1280,3328)   : N x N adj block per batch
//   blocks [3328,3840)   : zero off-diagonal N x A / A x N regions
__global__ __launch_bounds__(256) void k_simwb(const float* __restrict__ Xn,
                                               const float* __restrict__ memN_T,
                                               const float* __restrict__ mem_adj,
                                               const float* __restrict__ dmem_inv,
                                               const float* __restrict__ adj,
                                               const float* __restrict__ sc_adj,
                                               float* __restrict__ sim,
                                               float* __restrict__ simT,
                                               float* __restrict__ W) {
    __shared__ float smem[2 * 16 * (NK + 1)];   // 12.4 KB, reused per branch
    int bi = blockIdx.x, tid = threadIdx.x;
    int tx = tid & 15, ty = tid >> 4;
    if (bi < 256) {
        float (*xr)[NC] = (float(*)[NC])smem;
        int g0 = bi * 8;
        int b = g0 >> 8, n0 = g0 & 255;
        for (int i = tid; i < 8 * NC; i += 256) xr[i >> 7][i & 127] = Xn[(size_t)g0 * NC + i];
        __syncthreads();
        float acc0[8] = {0, 0, 0, 0, 0, 0, 0, 0};
        float acc1[8] = {0, 0, 0, 0, 0, 0, 0, 0};
        int a0 = tid, a1 = tid + 256;
        for (int c = 0; c < NC; c++) {
            float m0 = memN_T[c * NA + a0];
            float m1 = memN_T[c * NA + a1];
#pragma unroll
            for (int r = 0; r < 8; r++) { acc0[r] += xr[r][c] * m0; acc1[r] += xr[r][c] * m1; }
        }
#pragma unroll
        for (int r = 0; r < 8; r++) {
            sim[(size_t)(g0 + r) * NA + a0] = acc0[r];
            sim[(size_t)(g0 + r) * NA + a1] = acc1[r];
        }
        float* tp0 = simT + ((size_t)(b * NA + a0)) * NN + n0;
        float* tp1 = simT + ((size_t)(b * NA + a1)) * NN + n0;
        f32x4 u, v;
        u[0] = acc0[0]; u[1] = acc0[1]; u[2] = acc0[2]; u[3] = acc0[3];
        v[0] = acc0[4]; v[1] = acc0[5]; v[2] = acc0[6]; v[3] = acc0[7];
        *(f32x4*)tp0 = u; *(f32x4*)(tp0 + 4) = v;
        u[0] = acc1[0]; u[1] = acc1[1]; u[2] = acc1[2]; u[3] = acc1[3];
        v[0] = acc1[4]; v[1] = acc1[5]; v[2] = acc1[6]; v[3] = acc1[7];
        *(f32x4*)tp1 = u; *(f32x4*)(tp1 + 4) = v;
    } else if (bi < 1280) {
        float (*ta)[NK + 1] = (float(*)[NK + 1])smem;
        float (*tb)[NK + 1] = (float(*)[NK + 1])(smem + 16 * (NK + 1));
        int t = bi - 256;
        int a0 = (t >> 5) * 16, a1 = (t & 31) * 16;
        for (int i = tid; i < 16 * NK; i += 256) {
            int r = i / NK, j = i % NK;
            ta[r][j] = mem_adj[(a0 + r) * NK + j] * dmem_inv[j];
            tb[r][j] = mem_adj[(a1 + r) * NK + j];
        }
        __syncthreads();
        float s = 0.f;
        for (int j = 0; j < NK; j++) s += ta[ty][j] * tb[tx][j];
        int row = NN + a0 + ty, col = NN + a1 + tx;
        for (int b = 0; b < NB; b++) W[(size_t)b * NM * NM + (size_t)row * NM + col] = s;
    } else if (bi < 3328) {
        float (*ta)[NK + 1] = (float(*)[NK + 1])smem;
        float (*tb)[NK + 1] = (float(*)[NK + 1])(smem + 16 * (NK + 1));
        int t = bi - 1280;
        int n1 = (t & 15) * 16, n0 = ((t >> 4) & 15) * 16, b = t >> 8;
        const float* adjb = adj + (size_t)b * NN * NK;
        const float* scb = sc_adj + b * NK;
        for (int i = tid; i < 16 * NK; i += 256) {
            int r = i / NK, j = i % NK;
            ta[r][j] = adjb[(n0 + r) * NK + j] * scb[j];
            tb[r][j] = adjb[(n1 + r) * NK + j];
        }
        __syncthreads();
        float s = 0.f;
        for (int j = 0; j < NK; j++) s += ta[ty][j] * tb[tx][j];
        W[(size_t)b * NM * NM + (size_t)(n0 + ty) * NM + (n1 + tx)] = s;
    } else {
        int t = bi - 3328;               // [0, 512)
        int b = t >> 6;
        f32x4 z; z[0] = 0.f; z[1] = 0.f; z[2] = 0.f; z[3] = 0.f;
#pragma unroll
        for (int q = 0; q < 4; q++) {
            int v = (t & 63) * 1024 + q * 256 + tid;   // [0, 65536) f32x4 slots/batch
            int row, col4;
            if (v < 32768) { row = v >> 7; col4 = 64 + (v & 127); }
            else { int v2 = v - 32768; row = 256 + (v2 >> 6); col4 = v2 & 63; }
            *(f32x4*)(W + (size_t)b * NM * NM + (size_t)row * NM + col4 * 4) = z;
        }
    }
}

// ---- sortable key: higher value wins, tie -> lower index (== lax.top_k order) ----
__device__ __forceinline__ unsigned long long pack_key(float v, unsigned idx) {
    unsigned u = __float_as_uint(v);
    u = (u & 0x80000000u) ? ~u : (u | 0x80000000u);
    return ((unsigned long long)u << 32) | (unsigned long long)(0xFFFFFFFFu - idx);
}

__device__ __forceinline__ void ins4(unsigned long long v, unsigned long long* k) {
    if (v > k[3]) {
        if (v > k[1]) {
            if (v > k[0]) { k[3] = k[2]; k[2] = k[1]; k[1] = k[0]; k[0] = v; }
            else         { k[3] = k[2]; k[2] = k[1]; k[1] = v; }
        } else {
            if (v > k[2]) { k[3] = k[2]; k[2] = v; }
            else          { k[3] = v; }
        }
    }
}

__device__ __forceinline__ void merge_top4(unsigned long long* k) {
#pragma unroll
    for (int d = 1; d < 64; d <<= 1) {
        unsigned long long p0 = __shfl_xor(k[0], d, 64);
        unsigned long long p1 = __shfl_xor(k[1], d, 64);
        unsigned long long p2 = __shfl_xor(k[2], d, 64);
        unsigned long long p3 = __shfl_xor(k[3], d, 64);
        unsigned long long c0 = k[0] > p3 ? k[0] : p3;
        unsigned long long c1 = k[1] > p2 ? k[1] : p2;
        unsigned long long c2 = k[2] > p1 ? k[2] : p1;
        unsigned long long c3 = k[3] > p0 ? k[3] : p0;
        unsigned long long d0 = c0 > c2 ? c0 : c2, d2 = c0 > c2 ? c2 : c0;
        unsigned long long d1 = c1 > c3 ? c1 : c3, d3 = c1 > c3 ? c3 : c1;
        k[0] = d0 > d1 ? d0 : d1; k[1] = d0 > d1 ? d1 : d0;
        k[2] = d2 > d3 ? d2 : d3; k[3] = d2 > d3 ? d3 : d2;
    }
}

// ---- fused top-4 + cross-column clique scatter (after k_simwb) ----
__global__ __launch_bounds__(256) void k_knnrev(const float* __restrict__ sim,
                                                const float* __restrict__ simT,
                                                float* __restrict__ W) {
    int wid = (blockIdx.x * 256 + threadIdx.x) >> 6;
    int lane = threadIdx.x & 63;
    unsigned long long k[4] = {0, 0, 0, 0};
    const float cval = 1.0f / (5.0f + 1e-8f);
    int b, rr[5];
    if (wid < NB * NN) {
        b = wid >> 8;
        rr[0] = wid & 255;
        const float* row = sim + (size_t)wid * NA;
#pragma unroll
        for (int t = 0; t < NA / 64; t++) {
            int a = lane + 64 * t;
            ins4(pack_key(row[a], (unsigned)a), k);
        }
        merge_top4(k);
#pragma unroll
        for (int t = 0; t < 4; t++) rr[t + 1] = NN + (int)(0xFFFFFFFFu - (unsigned)k[t]);
    } else {
        int w2 = wid - NB * NN;              // b*NA + a
        b = w2 >> 9;
        rr[0] = NN + (w2 & 511);
        const float* row = simT + (size_t)w2 * NN;
#pragma unroll
        for (int t = 0; t < NN / 64; t++) {
            int n = lane + 64 * t;
            ins4(pack_key(row[n], (unsigned)n), k);
        }
        merge_top4(k);
#pragma unroll
        for (int t = 0; t < 4; t++) rr[t + 1] = (int)(0xFFFFFFFFu - (unsigned)k[t]);
    }
    if (lane < 25) {
        int i = lane / 5, j = lane - i * 5;
        atomicAdd(W + (size_t)b * NM * NM + (size_t)rr[i] * NM + rr[j], cval);
    }
}

// ---- fused: W(f32) -> W16(bf16) + dis = 1/sqrt(rowsum+1+eps); one wave per row ----
__global__ __launch_bounds__(256) void k_w16dis(const float* __restrict__ W,
                                                unsigned short* __restrict__ W16,
                                                float* __restrict__ dis) {
    int wid = (blockIdx.x * 256 + threadIdx.x) >> 6;  // b*NM + row
    int lane = threadIdx.x & 63;
    if (wid >= NB * NM) return;
    const float* row = W + (size_t)wid * NM;
    unsigned short* row16 = W16 + (size_t)wid * NM;
    float s = 0.f;
#pragma unroll
    for (int t = 0; t < 3; t++) {
        int e = (lane + t * 64) * 4;
        f32x4 v = *(const f32x4*)(row + e);
        s += (v[0] + v[1]) + (v[2] + v[3]);
        u16x4 o;
        o[0] = f2bf(v[0]); o[1] = f2bf(v[1]); o[2] = f2bf(v[2]); o[3] = f2bf(v[3]);
        *(u16x4*)(row16 + e) = o;
    }
    s = wave_reduce_add(s);
    if (lane == 0) dis[wid] = 1.0f / sqrtf(s + 1.0f + 1e-8f);
}

// ---- Z0[b,c,m] = dis[b,m]*joint (bf16, all m); Xh (B,C,N) = 0.9*feat (m<N only) ----
__global__ void k_y0(const float* __restrict__ feat, const float* __restrict__ tfT,
                     const float* __restrict__ dis, unsigned short* __restrict__ Z0,
                     float* __restrict__ Xh) {
    int bc = blockIdx.x;            // b*NC + c
    int b = bc >> 7, c = bc & 127;
    for (int m = threadIdx.x; m < NM; m += 256) {
        float v = (m < NN) ? feat[(size_t)bc * NN + m] : tfT[(size_t)c * NA + (m - NN)];
        Z0[(size_t)bc * NM + m] = f2bf(dis[b * NM + m] * v);
        if (m < NN) Xh[(size_t)bc * NN + m] = 0.9f * v;
    }
}

// ---- MFMA propagation on Z = D^-1/2 Y (full step):
//      s = W @ Zin ; o = dis*(s + Zin) ; Xh += coef*o (only m<N rows) ; Zout = dis*o
__global__ __launch_bounds__(256) void k_prop(const unsigned short* __restrict__ W16,
                                              const float* __restrict__ dis,
                                              const unsigned short* __restrict__ Zin,
                                              unsigned short* __restrict__ Zout,
                                              float* __restrict__ Xh, float coef) {
    int b = blockIdx.z;
    int m0 = blockIdx.x * 32;   // 24 tiles
    int c0 = blockIdx.y * 64;   // 2 tiles
    int tid = threadIdx.x;
    int w = tid >> 6, l = tid & 63;
    int wm = w >> 1, wc = w & 1;
    int lr = l & 15, lg = l >> 4;

    const unsigned short* Ap = W16 + ((size_t)b * NM + m0 + wm * 16 + lr) * NM + lg * 8;
    const unsigned short* Bp = Zin + ((size_t)b * NC + c0 + wc * 32 + lr) * NM + lg * 8;

    f32x4 acc[2];
#pragma unroll
    for (int f = 0; f < 2; f++) { acc[f][0] = 0.f; acc[f][1] = 0.f; acc[f][2] = 0.f; acc[f][3] = 0.f; }

    bf16x8 a0 = *(const bf16x8*)(Ap);
    bf16x8 b0[2];
#pragma unroll
    for (int f = 0; f < 2; f++) b0[f] = *(const bf16x8*)(Bp + (size_t)(f * 16) * NM);

    for (int k0 = 0; k0 < NM - 32; k0 += 32) {
        bf16x8 a1 = *(const bf16x8*)(Ap + k0 + 32);
        bf16x8 b1[2];
#pragma unroll
        for (int f = 0; f < 2; f++) b1[f] = *(const bf16x8*)(Bp + (size_t)(f * 16) * NM + k0 + 32);
#pragma unroll
        for (int f = 0; f < 2; f++)
            acc[f] = __builtin_amdgcn_mfma_f32_16x16x32_bf16(a0, b0[f], acc[f], 0, 0, 0);
        a0 = a1;
#pragma unroll
        for (int f = 0; f < 2; f++) b0[f] = b1[f];
    }
#pragma unroll
    for (int f = 0; f < 2; f++)
        acc[f] = __builtin_amdgcn_mfma_f32_16x16x32_bf16(a0, b0[f], acc[f], 0, 0, 0);

    int mb = m0 + wm * 16 + lg * 4;
    f32x4 dv = *(const f32x4*)(dis + b * NM + mb);
    bool doXh = (m0 < NN);          // m-tile 32-aligned: whole tile is < N or >= N
#pragma unroll
    for (int f = 0; f < 2; f++) {
        int c = c0 + wc * 32 + f * 16 + lr;
        size_t off = ((size_t)b * NC + c) * NM + mb;
        u16x4 zi = *(const u16x4*)(Zin + off);
        u16x4 zo;
        f32x4 xh;
        size_t offh = ((size_t)b * NC + c) * NN + mb;
        if (doXh) xh = *(const f32x4*)(Xh + offh);
#pragma unroll
        for (int r = 0; r < 4; r++) {
            float o = dv[r] * (acc[f][r] + bf2f(zi[r]));
            if (doXh) xh[r] += coef * o;
            zo[r] = f2bf(dv[r] * o);
        }
        if (doXh) *(f32x4*)(Xh + offh) = xh;
        *(u16x4*)(Zout + off) = zo;
    }
}

// ---- last propagation: only m<256 matters; writes X_hat (B,C,N) directly ----
__global__ __launch_bounds__(256) void k_prop_last(const unsigned short* __restrict__ W16,
                                                   const float* __restrict__ dis,
                                                   const unsigned short* __restrict__ Zin,
                                                   const float* __restrict__ Xh,
                                                   float* __restrict__ out_xhat, float coef) {
    int b = blockIdx.z;
    int m0 = blockIdx.x * 32;   // 8 tiles -> m < 256
    int c0 = blockIdx.y * 64;
    int tid = threadIdx.x;
    int w = tid >> 6, l = tid & 63;
    int wm = w >> 1, wc = w & 1;
    int lr = l & 15, lg = l >> 4;

    const unsigned short* Ap = W16 + ((size_t)b * NM + m0 + wm * 16 + lr) * NM + lg * 8;
    const unsigned short* Bp = Zin + ((size_t)b * NC + c0 + wc * 32 + lr) * NM + lg * 8;

    f32x4 acc[2];
#pragma unroll
    for (int f = 0; f < 2; f++) { acc[f][0] = 0.f; acc[f][1] = 0.f; acc[f][2] = 0.f; acc[f][3] = 0.f; }

    bf16x8 a0 = *(const bf16x8*)(Ap);
    bf16x8 b0[2];
#pragma unroll
    for (int f = 0; f < 2; f++) b0[f] = *(const bf16x8*)(Bp + (size_t)(f * 16) * NM);

    for (int k0 = 0; k0 < NM - 32; k0 += 32) {
        bf16x8 a1 = *(const bf16x8*)(Ap + k0 + 32);
        bf16x8 b1[2];
#pragma unroll
        for (int f = 0; f < 2; f++) b1[f] = *(const bf16x8*)(Bp + (size_t)(f * 16) * NM + k0 + 32);
#pragma unroll
        for (int f = 0; f < 2; f++)
            acc[f] = __builtin_amdgcn_mfma_f32_16x16x32_bf16(a0, b0[f], acc[f], 0, 0, 0);
        a0 = a1;
#pragma unroll
        for (int f = 0; f < 2; f++) b0[f] = b1[f];
    }
#pragma unroll
    for (int f = 0; f < 2; f++)
        acc[f] = __builtin_amdgcn_mfma_f32_16x16x32_bf16(a0, b0[f], acc[f], 0, 0, 0);

    int mb = m0 + wm * 16 + lg * 4;   // < 256
    f32x4 dv = *(const f32x4*)(dis + b * NM + mb);
#pragma unroll
    for (int f = 0; f < 2; f++) {
        int c = c0 + wc * 32 + f * 16 + lr;
        size_t offM = ((size_t)b * NC + c) * NM + mb;
        u16x4 zi = *(const u16x4*)(Zin + offM);
        f32x4 xh = *(const f32x4*)(Xh + ((size_t)b * NC + c) * NN + mb);
        f32x4 ov;
#pragma unroll
        for (int r = 0; r < 4; r++) {
            float o = dv[r] * (acc[f][r] + bf2f(zi[r]));
            ov[r] = xh[r] + coef * o;
        }
        *(f32x4*)(out_xhat + ((size_t)b * NC + c) * NN + mb) = ov;
    }
}

// ---- X_E[b,k,c] = inv_edge[b,k] * sum_n (adj[b,n,k]*isn[b,n]) * Xhat[b,c,n] ----
__global__ __launch_bounds__(256) void k_xe(const float* __restrict__ Xhat,
                                            const float* __restrict__ adj,
                                            const float* __restrict__ isn,
                                            const float* __restrict__ inv_edge,
                                            float* __restrict__ outE) {
    __shared__ float ta[16][17];  // [n_local][k_local]
    __shared__ float tz[16][17];  // [c_local][n_local]
    int b = blockIdx.z;
    int k0 = blockIdx.y * 16;     // 6 tiles
    int c0 = blockIdx.x * 16;     // 8 tiles
    int tx = threadIdx.x & 15;
    int ty = threadIdx.x >> 4;
    float acc = 0.f;
    for (int n0 = 0; n0 < NN; n0 += 16) {
        int n = n0 + ty;
        ta[ty][tx] = adj[(size_t)(b * NN + n) * NK + k0 + tx] * isn[b * NN + n];
        tz[ty][tx] = Xhat[((size_t)b * NC + c0 + ty) * NN + n0 + tx];
        __syncthreads();
#pragma unroll
        for (int nn = 0; nn < 16; nn++) acc += ta[nn][ty] * tz[tx][nn];
        __syncthreads();
    }
    int k = k0 + ty, c = c0 + tx;
    outE[(size_t)(b * NK + k) * NC + c] = inv_edge[b * NK + k] * acc;
}

extern "C" void kernel_launch(void* const* d_in, const int* in_sizes, int n_in,
                              void* d_out, int out_size, void* d_ws, size_t ws_size,
                              hipStream_t stream) {
    (void)in_sizes; (void)n_in; (void)out_size; (void)ws_size;
    const float* features = (const float*)d_in[0];  // (B,C,N)
    const float* adj      = (const float*)d_in[1];  // (B,N,K)
    const float* tf       = (const float*)d_in[2];  // (A,C)
    const float* mem_adj  = (const float*)d_in[3];  // (A,K)
    float* out_xhat = (float*)d_out;                 // (B,C,N)
    float* out_xe   = out_xhat + (size_t)NB * NC * NN;  // (B,K,C)

    float* p = (float*)d_ws;
    float* memN_T  = p; p += (size_t)NC * NA;
    float* tfT     = p; p += (size_t)NC * NA;
    float* Xn      = p; p += (size_t)NB * NN * NC;
    float* sim     = p; p += (size_t)NB * NN * NA;
    float* simT    = p; p += (size_t)NB * NN * NA;
    float* sc_adj  = p; p += NB * NK;
    float* inv_edge= p; p += NB * NK;
    float* dmem_inv= p; p += NK;
    float* isn     = p; p += NB * NN;
    float* dis     = p; p += NB * NM;
    float* W       = p; p += (size_t)NB * NM * NM;
    float* Xh      = p; p += (size_t)NB * NC * NN;   // (B,C,N) f32 (m<N only)
    unsigned short* W16 = (unsigned short*)p;        // (B,M,M) bf16
    unsigned short* Z0  = W16 + (size_t)NB * NM * NM;
    unsigned short* Z1  = Z0 + (size_t)NB * NC * NM;

    k_normdeg<<<NORM_BLKS + (DEG_WAVES + 1) / 2, 128, 0, stream>>>(
        tf, features, mem_adj, adj, memN_T, tfT, Xn, dmem_inv, sc_adj, inv_edge, isn);
    k_simwb<<<3840, 256, 0, stream>>>(Xn, memN_T, mem_adj, dmem_inv, adj, sc_adj,
                                      sim, simT, W);
    k_knnrev<<<(NB * NN + NB * NA) / 4, 256, 0, stream>>>(sim, simT, W);
    k_w16dis<<<NB * NM / 4, 256, 0, stream>>>(W, W16, dis);
    k_y0<<<NB * NC, 256, 0, stream>>>(features, tfT, dis, Z0, Xh);
    dim3 pg(NM / 32, NC / 64, NB);
    k_prop<<<pg, 256, 0, stream>>>(W16, dis, Z0, Z1, Xh, 0.09f);
    k_prop<<<pg, 256, 0, stream>>>(W16, dis, Z1, Z0, Xh, 0.009f);
    dim3 pl(NN / 32, NC / 64, NB);
    k_prop_last<<<pl, 256, 0, stream>>>(W16, dis, Z0, Xh, out_xhat, 0.001f);
    k_xe<<<dim3(NC / 16, NK / 16, NB), 256, 0, stream>>>(out_xhat, adj, isn, inv_edge, out_xe);
}